// Round 1
// baseline (1941.929 us; speedup 1.0000x reference)
//
#include <hip/hip_runtime.h>
#include <math.h>

#define B 2
#define Q 15
#define U 20
#define C 64
#define HW 441
#define NW 5
#define MU (U*HW)      // 8820
#define MS HW          // 441
#define NJ (NW*MS)     // 2205
#define PD 64
#define LCAP NJ        // max selected per (b,n)
#define LTCAP 2688     // 441+2205=2646 rounded up to 64
#define STS 68         // LDS S-tile stride (68%4==0 -> float4-aligned rows)
#define NEGF (-3.402823466e38f)

// ---------------- device scratch (static; fully rewritten every call) -------
__device__ float g_rnu[B*MU];
__device__ float g_rns[B*NJ];
__device__ unsigned long long g_snearpack[B*NJ];
__device__ int   g_unear[B*MU];
__device__ int   g_cls[B*MU];
__device__ int   g_clssel[B*MU];
__device__ int   g_counts[B*NW];
__device__ int   g_L[1];
__device__ int   g_selidx[B*NW*LCAP];
__device__ float g_ksup[(size_t)B*NW*PD*LTCAP];
__device__ float g_vsup[(size_t)B*NW*PD*LTCAP];
__device__ float g_vbar[B*NW*PD];
__device__ float g_qproj[(size_t)B*Q*PD*MS];
__device__ float g_vqn[(size_t)B*Q*PD*MS];
__device__ unsigned long long g_rowpack[(size_t)B*Q*NW*MS];
__device__ int   g_snear2[(size_t)B*Q*NW*LTCAP];
__device__ int   g_qmask[B*Q*MS];
__device__ unsigned g_cmax[(size_t)B*Q*NW*448];
__device__ float g_logits[B*Q*NW];

__device__ __forceinline__ unsigned enc_f(float f){
  unsigned b=__float_as_uint(f);
  return (b&0x80000000u)? ~b : (b|0x80000000u);
}
__device__ __forceinline__ float dec_f(unsigned k){
  unsigned b=(k&0x80000000u)?(k^0x80000000u):~k;
  return __uint_as_float(b);
}

// ---------------- init: zero the atomic-combined buffers --------------------
__global__ void k_init(){
  int i=blockIdx.x*256+threadIdx.x;
  if (i<B*NJ) g_snearpack[i]=0ull;
  if (i<B*Q*NW*MS) g_rowpack[i]=0ull;
  if (i<B*Q*NW*448) g_cmax[i]=0u;
  if (i==0) g_L[0]=0;
}

// ---------------- K1: inverse column norms (raw dots scaled later) ----------
__global__ void k_norms(const float* __restrict__ sup, const float* __restrict__ unl){
  int i=blockIdx.x*256+threadIdx.x;
  if (i<B*MU){
    int b=i/MU, m=i%MU, ui=m/HW, p=m%HW;
    const float* base=unl+((size_t)(b*U+ui)*C)*HW+p;
    float ss=0.f;
    for (int c=0;c<C;c++){ float x=base[(size_t)c*HW]; ss+=x*x; }
    g_rnu[i]=1.f/fmaxf(sqrtf(ss),1e-12f);
  }
  if (i<B*NJ){
    int b=i/NJ, j=i%NJ, n=j/MS, s=j%MS;
    const float* base=sup+((size_t)(b*NW+n)*C)*HW+s;
    float ss=0.f;
    for (int c=0;c<C;c++){ float x=base[(size_t)c*HW]; ss+=x*x; }
    g_rns[i]=1.f/fmaxf(sqrtf(ss),1e-12f);
  }
}

// ---------------- K2: u2s pass (s_near via atomics; u_near+cls per row) -----
__global__ __launch_bounds__(256) void k_u2s(const float* __restrict__ sup, const float* __restrict__ unl){
  int b=blockIdx.x/138;
  int mb=(blockIdx.x%138)*64;
  int tid=threadIdx.x, tm=tid>>4, tl=tid&15;
  __shared__ float Ut[4096];      // [c][mm] (pre-scaled by rnu)
  __shared__ float Pt[4096];      // [c][jj] (pre-scaled by rns)
  __shared__ float St[64*STS];
  for (int k=tid;k<4096;k+=256){
    int c=k>>6, mm=k&63, m=mb+mm; float v=0.f;
    if (m<MU){ int ui=m/HW, p=m%HW; v=unl[((size_t)(b*U+ui)*C+c)*HW+p]*g_rnu[b*MU+m]; }
    Ut[c*64+mm]=v;
  }
  int mv=min(64,MU-mb);
  float bestv=NEGF; int bestj=0;
  float c0=NEGF,c1=NEGF,c2=NEGF,c3=NEGF,c4=NEGF;
  for (int jc=0;jc<35;jc++){
    int j0=jc*64, jv=min(64,NJ-j0);
    __syncthreads();
    for (int k=tid;k<4096;k+=256){
      int c=k>>6, jj=k&63, j=j0+jj; float v=0.f;
      if (jj<jv){ int n=j/MS, s=j%MS; v=sup[((size_t)(b*NW+n)*C+c)*HW+s]*g_rns[b*NJ+j]; }
      Pt[c*64+jj]=v;
    }
    __syncthreads();
    float s[4][4]={};
    for (int c=0;c<64;c++){
      float a[4],bv[4];
      *(float4*)a=*(const float4*)&Ut[c*64+tm*4];
      *(float4*)bv=*(const float4*)&Pt[c*64+tl*4];
      #pragma unroll
      for (int i=0;i<4;i++)
        #pragma unroll
        for (int j=0;j<4;j++) s[i][j]=fmaf(a[i],bv[j],s[i][j]);
    }
    #pragma unroll
    for (int i=0;i<4;i++)
      #pragma unroll
      for (int j=0;j<4;j++) St[(tm*4+i)*STS+tl*4+j]=s[i][j];
    __syncthreads();
    if (tid<64){
      int jj=tid;
      if (jj<jv){
        float bv=NEGF; int bm=0;
        for (int mm=0;mm<mv;mm++){ float v=St[mm*STS+jj]; if (v>bv){bv=v;bm=mb+mm;} }
        unsigned long long pk=((unsigned long long)enc_f(bv)<<32)|(unsigned)~(unsigned)bm;
        atomicMax(&g_snearpack[b*NJ+j0+jj],pk);
      }
    } else if (tid<128){
      int mm=tid-64;
      if (mm<mv){
        for (int jl=0;jl<jv;jl++){
          float v=St[mm*STS+jl];
          int j=j0+jl;
          if (v>bestv){bestv=v;bestj=j;}
          int nn=j/MS;
          if (nn==0){ if(v>c0)c0=v; } else if (nn==1){ if(v>c1)c1=v; }
          else if (nn==2){ if(v>c2)c2=v; } else if (nn==3){ if(v>c3)c3=v; }
          else { if(v>c4)c4=v; }
        }
      }
    }
  }
  if (tid>=64 && tid<128){
    int mm=tid-64;
    if (mm<mv){
      int m=mb+mm;
      g_unear[b*MU+m]=bestj;
      int cl=0; float bb=c0;
      if (c1>bb){bb=c1;cl=1;}
      if (c2>bb){bb=c2;cl=2;}
      if (c3>bb){bb=c3;cl=3;}
      if (c4>bb){bb=c4;cl=4;}
      g_cls[b*MU+m]=cl;
    }
  }
}

// ---------------- K3: mutual-NN check --------------------------------------
__global__ void k_mutual(){
  int i=blockIdx.x*256+threadIdx.x;
  if (i>=B*MU) return;
  int b=i/MU, m=i%MU;
  int j=g_unear[i];
  unsigned long long pk=g_snearpack[b*NJ+j];
  int sm_=(int)~(unsigned)(pk&0xFFFFFFFFull);
  g_clssel[i]=(sm_==m)?g_cls[i]:-1;
}

// ---------------- K4: stable compaction per (b,n); counts; L ----------------
__global__ __launch_bounds__(256) void k_compact(){
  int b=blockIdx.x/NW, n=blockIdx.x%NW;
  int tid=threadIdx.x, lane=tid&63, w=tid>>6;
  __shared__ int wtot[4];
  int base=0;
  for (int m0=0;m0<MU;m0+=256){
    int m=m0+tid;
    bool flag=(m<MU)&&(g_clssel[b*MU+m]==n);
    unsigned long long bal=__ballot(flag);
    if (lane==0) wtot[w]=(int)__popcll(bal);
    __syncthreads();
    int wpre=0, tot=0;
    #pragma unroll
    for (int ww=0;ww<4;ww++){ if (ww<w) wpre+=wtot[ww]; tot+=wtot[ww]; }
    if (flag){
      int pre=(int)__popcll(bal&((1ull<<lane)-1ull));
      g_selidx[(b*NW+n)*LCAP+base+wpre+pre]=m;
    }
    base+=tot;
    __syncthreads();
  }
  if (tid==0){ g_counts[b*NW+n]=base; atomicMax(&g_L[0],base); }
}

// ---------------- K5: k_sup / v_sup (zero-filled to LTCAP) ------------------
__global__ __launch_bounds__(64) void k_kv(const float* __restrict__ sup, const float* __restrict__ unl,
                                           const float* __restrict__ kw, const float* __restrict__ vw){
  int blk=blockIdx.x;
  int lb=blk%(LTCAP/64); blk/=(LTCAP/64);
  int n=blk%NW, b=blk/NW;
  int tid=threadIdx.x;
  int l=lb*64+tid;
  int cnt=g_counts[b*NW+n];
  __shared__ float F[4096];     // [c][tid]
  for (int c=0;c<C;c++){
    float v=0.f;
    if (l<MS) v=sup[((size_t)(b*NW+n)*C+c)*HW+l];
    else if (l<MS+cnt){
      int mg=g_selidx[(b*NW+n)*LCAP+(l-MS)];
      int ui=mg/HW, p=mg%HW;
      v=unl[((size_t)(b*U+ui)*C+c)*HW+p];
    }
    F[c*64+tid]=v;
  }
  size_t ob=((size_t)(b*NW+n)*PD)*LTCAP+l;
  for (int o=0;o<PD;o++){
    float ka=0.f, va=0.f;
    for (int c=0;c<C;c++){ float f=F[c*64+tid]; ka=fmaf(kw[o*C+c],f,ka); va=fmaf(vw[o*C+c],f,va); }
    g_ksup[ob+(size_t)o*LTCAP]=ka;
    g_vsup[ob+(size_t)o*LTCAP]=va;
  }
}

// ---------------- K5b: vbar = (1/Lt) * sum_l v_sup --------------------------
__global__ __launch_bounds__(64) void k_vbar(){
  int blk=blockIdx.x;
  int o=blk%PD; blk/=PD;
  int n=blk%NW, b=blk/NW;
  int cnt=g_counts[b*NW+n];
  int Lt=MS+g_L[0];
  const float* row=&g_vsup[((size_t)(b*NW+n)*PD+o)*LTCAP];
  float s=0.f;
  for (int l=threadIdx.x;l<MS+cnt;l+=64) s+=row[l];
  #pragma unroll
  for (int off=32;off;off>>=1) s+=__shfl_down(s,off);
  if (threadIdx.x==0) g_vbar[(b*NW+n)*PD+o]=s/(float)Lt;
}

// ---------------- K6: q_proj and normalized v_query -------------------------
__global__ __launch_bounds__(64) void k_qproj(const float* __restrict__ qx, const float* __restrict__ qw,
                                              const float* __restrict__ vw){
  int blk=blockIdx.x;
  int mt=blk%7; blk/=7;
  int q=blk%Q, b=blk/Q;
  int tid=threadIdx.x, m=mt*64+tid;
  __shared__ float F[4096];
  for (int c=0;c<C;c++){
    float v=(m<MS)?qx[((size_t)(b*Q+q)*C+c)*HW+m]:0.f;
    F[c*64+tid]=v;
  }
  if (m>=MS) return;
  size_t ob=((size_t)(b*Q+q)*PD)*MS+m;
  float ss=0.f;
  for (int o=0;o<PD;o++){
    float qa=0.f, va=0.f;
    for (int c=0;c<C;c++){ float f=F[c*64+tid]; qa=fmaf(qw[o*C+c],f,qa); va=fmaf(vw[o*C+c],f,va); }
    g_qproj[ob+(size_t)o*MS]=qa;
    g_vqn[ob+(size_t)o*MS]=va;
    ss=fmaf(va,va,ss);
  }
  float rn=1.f/(sqrtf(ss)+1e-16f);
  for (int o=0;o<PD;o++) g_vqn[ob+(size_t)o*MS]*=rn;
}

// ---------------- K7: pass A — simi row-best (q_near) & col-best (s_near2) --
__global__ __launch_bounds__(256) void k_passA(){
  int blk=blockIdx.x;
  int lcg=blk%11; blk/=11;
  int n=blk%NW; blk/=NW;
  int q=blk%Q; int b=blk/Q;
  int Lt=MS+g_L[0];
  int nch=(Lt+63)>>6;
  int lc0=lcg*4;
  if (lc0>=nch) return;
  int lc1=min(lc0+4,nch);
  int tid=threadIdx.x, tm=tid>>4, tl=tid&15;
  int bqn=(b*Q+q)*NW+n;
  __shared__ float Qt[4096];
  __shared__ float Kt[4096];
  __shared__ float St[64*STS];
  __shared__ float rowv[448];
  __shared__ int   rowi[448];
  for (int i=tid;i<448;i+=256){ rowv[i]=NEGF; rowi[i]=0; }
  const size_t qb=(size_t)(b*Q+q)*PD*MS;
  const size_t kb=(size_t)(b*NW+n)*PD*LTCAP;
  for (int lc=lc0;lc<lc1;lc++){
    int l0=lc<<6, lv=min(64,Lt-l0);
    __syncthreads();
    for (int k=tid;k<4096;k+=256){ int o=k>>6, ll=k&63; Kt[k]=g_ksup[kb+(size_t)o*LTCAP+(l0+ll)]; }
    float cbv=NEGF; int cbi=0;
    for (int mt=0;mt<7;mt++){
      __syncthreads();
      for (int k=tid;k<4096;k+=256){ int o=k>>6, mm=k&63, m=mt*64+mm; Qt[k]=(m<MS)?g_qproj[qb+(size_t)o*MS+m]:0.f; }
      __syncthreads();
      float s[4][4]={};
      for (int c=0;c<64;c++){
        float a[4],bv[4];
        *(float4*)a=*(const float4*)&Qt[c*64+tm*4];
        *(float4*)bv=*(const float4*)&Kt[c*64+tl*4];
        #pragma unroll
        for (int i=0;i<4;i++)
          #pragma unroll
          for (int j=0;j<4;j++) s[i][j]=fmaf(a[i],bv[j],s[i][j]);
      }
      #pragma unroll
      for (int i=0;i<4;i++)
        #pragma unroll
        for (int j=0;j<4;j++) St[(tm*4+i)*STS+tl*4+j]=s[i][j]*0.125f;
      __syncthreads();
      int mv=min(64,MS-mt*64);
      if (tid<64){
        if (l0+tid<Lt){
          for (int mm=0;mm<mv;mm++){ float v=St[mm*STS+tid]; if (v>cbv){cbv=v;cbi=mt*64+mm;} }
        }
      } else if (tid<128){
        int mm=tid-64;
        if (mm<mv){
          float rv=rowv[mt*64+mm]; int riv=rowi[mt*64+mm];
          for (int jl=0;jl<lv;jl++){ float v=St[mm*STS+jl]; if (v>rv){rv=v;riv=l0+jl;} }
          rowv[mt*64+mm]=rv; rowi[mt*64+mm]=riv;
        }
      }
    }
    if (tid<64 && l0+tid<Lt) g_snear2[(size_t)bqn*LTCAP+l0+tid]=cbi;
  }
  __syncthreads();
  for (int m=tid;m<MS;m+=256){
    float v=rowv[m];
    if (v>-1e37f){
      unsigned long long pk=((unsigned long long)enc_f(v)<<32)|(unsigned)~(unsigned)rowi[m];
      atomicMax(&g_rowpack[(size_t)bqn*MS+m],pk);
    }
  }
}

// ---------------- K8: q_mask ------------------------------------------------
__global__ __launch_bounds__(256) void k_qmask(){
  int bq=blockIdx.x;
  for (int m=threadIdx.x;m<MS;m+=256){
    float bv=NEGF; int bn=0, bl=0;
    #pragma unroll
    for (int n=0;n<NW;n++){
      unsigned long long pk=g_rowpack[(size_t)(bq*NW+n)*MS+m];
      float v=dec_f((unsigned)(pk>>32));
      int l=(int)~(unsigned)(pk&0xFFFFFFFFull);
      if (v>bv){bv=v;bn=n;bl=l;}
    }
    int s2=g_snear2[(size_t)(bq*NW+bn)*LTCAP+bl];
    g_qmask[bq*MS+m]=(s2==m)?1:0;
  }
}

// ---------------- K9: pass B — online softmax, PV, normalize, simi2 max -----
__global__ __launch_bounds__(256) void k_passB(){
  int blk=blockIdx.x;
  int mt=blk%7; blk/=7;
  int n=blk%NW; blk/=NW;
  int q=blk%Q; int b=blk/Q;
  int bq=b*Q+q, bqn=bq*NW+n;
  int Lt=MS+g_L[0];
  int nch=(Lt+63)>>6;
  int tid=threadIdx.x, tm=tid>>4, tl=tid&15;
  __shared__ float Qt[4096];
  __shared__ float KV[4096];
  __shared__ float St[64*STS];
  __shared__ float mx[64], sm[64], al[64], rn_[64];
  const size_t qb=(size_t)bq*PD*MS;
  const size_t kb=(size_t)(b*NW+n)*PD*LTCAP;
  for (int k=tid;k<4096;k+=256){ int o=k>>6, mm=k&63, m=mt*64+mm; Qt[k]=(m<MS)?g_qproj[qb+(size_t)o*MS+m]:0.f; }
  if (tid<64){ mx[tid]=NEGF; sm[tid]=0.f; }
  float acc[4][4]={};
  for (int lc=0;lc<nch;lc++){
    int l0=lc<<6, lv=min(64,Lt-l0);
    __syncthreads();
    for (int k=tid;k<4096;k+=256){ int o=k>>6, ll=k&63; KV[k]=g_ksup[kb+(size_t)o*LTCAP+(l0+ll)]; }
    __syncthreads();
    float s[4][4]={};
    for (int c=0;c<64;c++){
      float a[4],bv[4];
      *(float4*)a=*(const float4*)&Qt[c*64+tm*4];
      *(float4*)bv=*(const float4*)&KV[c*64+tl*4];
      #pragma unroll
      for (int i=0;i<4;i++)
        #pragma unroll
        for (int j=0;j<4;j++) s[i][j]=fmaf(a[i],bv[j],s[i][j]);
    }
    #pragma unroll
    for (int i=0;i<4;i++)
      #pragma unroll
      for (int j=0;j<4;j++){
        int ll=tl*4+j;
        St[(tm*4+i)*STS+ll]=(ll<lv)?s[i][j]*0.125f:NEGF;
      }
    __syncthreads();
    if (tid<64){
      float old=mx[tid], cmx=old;
      for (int l=0;l<lv;l++){ float v=St[tid*STS+l]; if (v>cmx) cmx=v; }
      float a=(old<-1e37f)?0.f:__expf(old-cmx);
      float ps=0.f;
      for (int l=0;l<64;l++){
        float e=0.f;
        if (l<lv) e=__expf(St[tid*STS+l]-cmx);
        St[tid*STS+l]=e; ps+=e;
      }
      sm[tid]=sm[tid]*a+ps; mx[tid]=cmx; al[tid]=a;
    }
    __syncthreads();
    for (int k=tid;k<4096;k+=256){ int o=k>>6, ll=k&63; KV[k]=g_vsup[kb+(size_t)o*LTCAP+(l0+ll)]; }
    __syncthreads();
    float aa[4];
    #pragma unroll
    for (int i=0;i<4;i++) aa[i]=al[tm*4+i];
    #pragma unroll
    for (int i=0;i<4;i++)
      #pragma unroll
      for (int j=0;j<4;j++) acc[i][j]*=aa[i];
    for (int l4=0;l4<64;l4+=4){
      float p[4][4], v[4][4];
      #pragma unroll
      for (int i=0;i<4;i++) *(float4*)p[i]=*(const float4*)&St[(tm*4+i)*STS+l4];
      #pragma unroll
      for (int j=0;j<4;j++) *(float4*)v[j]=*(const float4*)&KV[(tl*4+j)*64+l4];
      #pragma unroll
      for (int i=0;i<4;i++)
        #pragma unroll
        for (int j=0;j<4;j++)
          #pragma unroll
          for (int u=0;u<4;u++) acc[i][j]=fmaf(p[i][u],v[j][u],acc[i][j]);
    }
    __syncthreads();
  }
  // epilogue: aligned rows -> St region (stride STS), normalize, simi2 max
  __syncthreads();
  #pragma unroll
  for (int i=0;i<4;i++){
    int m=mt*64+tm*4+i;
    int qm=(m<MS)?g_qmask[bq*MS+m]:0;
    float smi=sm[tm*4+i];
    #pragma unroll
    for (int j=0;j<4;j++){
      int o=tl*4+j;
      float v=qm?(acc[i][j]/smi):g_vbar[(b*NW+n)*PD+o];
      St[(tm*4+i)*STS+o]=v;
    }
  }
  __syncthreads();
  if (tid<64){
    float ss=0.f;
    for (int o=0;o<PD;o++){ float v=St[tid*STS+o]; ss=fmaf(v,v,ss); }
    rn_[tid]=1.f/(sqrtf(ss)+1e-16f);
  }
  __syncthreads();
  for (int kt=0;kt<7;kt++){
    __syncthreads();
    for (int k=tid;k<4096;k+=256){ int o=k>>6, kk=k&63, kg=kt*64+kk; KV[k]=(kg<MS)?g_vqn[qb+(size_t)o*MS+kg]:0.f; }
    __syncthreads();
    float d[4][4]={};
    for (int o4=0;o4<64;o4+=4){
      float a[4][4];
      #pragma unroll
      for (int i=0;i<4;i++) *(float4*)a[i]=*(const float4*)&St[(tm*4+i)*STS+o4];
      #pragma unroll
      for (int u=0;u<4;u++){
        float vv[4];
        *(float4*)vv=*(const float4*)&KV[(o4+u)*64+tl*4];
        #pragma unroll
        for (int i=0;i<4;i++)
          #pragma unroll
          for (int j=0;j<4;j++) d[i][j]=fmaf(a[i][u],vv[j],d[i][j]);
      }
    }
    float rnl[4]; int mok[4];
    #pragma unroll
    for (int i=0;i<4;i++){ rnl[i]=rn_[tm*4+i]; mok[i]=(mt*64+tm*4+i<MS); }
    #pragma unroll
    for (int j=0;j<4;j++){
      int kg=kt*64+tl*4+j;
      if (kg<MS){
        float mvv=NEGF; int any=0;
        #pragma unroll
        for (int i=0;i<4;i++){
          if (mok[i]){ float dv=d[i][j]*rnl[i]; if (!any||dv>mvv){mvv=dv;any=1;} }
        }
        if (any) atomicMax(&g_cmax[(size_t)bqn*448+kg],enc_f(mvv));
      }
    }
  }
}

// ---------------- K9b: logits -----------------------------------------------
__global__ __launch_bounds__(256) void k_logits(){
  int bqn=blockIdx.x;
  __shared__ float red[256];
  float p=0.f;
  for (int k=threadIdx.x;k<MS;k+=256){
    float v=dec_f(g_cmax[(size_t)bqn*448+k]);
    p+=(v+1.f)*0.5f;
  }
  red[threadIdx.x]=p; __syncthreads();
  for (int s=128;s;s>>=1){ if (threadIdx.x<s) red[threadIdx.x]+=red[threadIdx.x+s]; __syncthreads(); }
  if (threadIdx.x==0) g_logits[bqn]=red[0];
}

// ---------------- K10: NLL loss ---------------------------------------------
__global__ void k_loss(const int* __restrict__ qy, float* __restrict__ out){
  int t=threadIdx.x;
  float lp=0.f;
  if (t<B*Q){
    int y=qy[t];
    float xv[NW]; float mxv=NEGF;
    #pragma unroll
    for (int n=0;n<NW;n++){ xv[n]=g_logits[t*NW+n]*5.f; mxv=fmaxf(mxv,xv[n]); }
    float s=0.f, xy=0.f;
    #pragma unroll
    for (int n=0;n<NW;n++){ s+=__expf(xv[n]-mxv); if (n==y) xy=xv[n]; }
    lp=xy-mxv-logf(s);
  }
  #pragma unroll
  for (int off=32;off;off>>=1) lp+=__shfl_down(lp,off);
  if (t==0) out[0]=-lp/(float)(B*Q);
}

extern "C" void kernel_launch(void* const* d_in, const int* in_sizes, int n_in,
                              void* d_out, int out_size, void* d_ws, size_t ws_size,
                              hipStream_t stream) {
  (void)in_sizes; (void)n_in; (void)out_size; (void)d_ws; (void)ws_size;
  const float* sup=(const float*)d_in[0];
  const float* qx =(const float*)d_in[2];
  const int*   qy =(const int*)d_in[3];
  const float* unl=(const float*)d_in[4];
  const float* kw =(const float*)d_in[5];
  const float* qw =(const float*)d_in[6];
  const float* vw =(const float*)d_in[7];
  float* out=(float*)d_out;

  k_init   <<<263,256,0,stream>>>();
  k_norms  <<<69,256,0,stream>>>(sup,unl);
  k_u2s    <<<B*138,256,0,stream>>>(sup,unl);
  k_mutual <<<69,256,0,stream>>>();
  k_compact<<<B*NW,256,0,stream>>>();
  k_kv     <<<B*NW*(LTCAP/64),64,0,stream>>>(sup,unl,kw,vw);
  k_vbar   <<<B*NW*PD,64,0,stream>>>();
  k_qproj  <<<B*Q*7,64,0,stream>>>(qx,qw,vw);
  k_passA  <<<B*Q*NW*11,256,0,stream>>>();
  k_qmask  <<<B*Q,256,0,stream>>>();
  k_passB  <<<B*Q*NW*7,256,0,stream>>>();
  k_logits <<<B*Q*NW,256,0,stream>>>();
  k_loss   <<<1,64,0,stream>>>(qy,out);
}

// Round 2
// 1130.972 us; speedup vs baseline: 1.7170x; 1.7170x over previous
//
#include <hip/hip_runtime.h>
#include <math.h>

#define B 2
#define Q 15
#define U 20
#define C 64
#define HW 441
#define NW 5
#define MU (U*HW)      // 8820
#define MS HW          // 441
#define NJ (NW*MS)     // 2205
#define PD 64
#define LCAP NJ
#define LTCAP 2688     // 441+2205=2646 rounded up to 64
#define MSP 448        // padded MS for float4-aligned strides
#define NEGF (-3.402823466e38f)

// ---------------- device scratch (rewritten every call before any read) -----
__device__ float g_rnu[B*MU];
__device__ float g_rns[B*NJ];
__device__ unsigned long long g_snearpack[B*NJ];
__device__ int   g_unear[B*MU];
__device__ int   g_clssel[B*MU];
__device__ int   g_counts[B*NW];
__device__ int   g_L[1];
__device__ int   g_selidx[B*NW*LCAP];
__device__ float g_ksup[(size_t)B*NW*PD*LTCAP];
__device__ float g_vsup[(size_t)B*NW*PD*LTCAP];
__device__ float g_vbarn[B*NW*PD];
__device__ float g_qproj[(size_t)B*Q*PD*MSP];
__device__ float g_vqn[(size_t)B*Q*PD*MSP];
__device__ unsigned long long g_rowpack[(size_t)B*Q*NW*MSP];
__device__ int   g_snear2[(size_t)B*Q*NW*LTCAP];
__device__ int   g_qmrows[B*Q*MSP];
__device__ int   g_qmcount[B*Q];
__device__ unsigned g_cmax[(size_t)B*Q*NW*MSP];
__device__ float g_logits[B*Q*NW];

__device__ __forceinline__ unsigned enc_f(float f){
  unsigned b=__float_as_uint(f);
  return (b&0x80000000u)? ~b : (b|0x80000000u);
}
__device__ __forceinline__ float dec_f(unsigned k){
  unsigned b=(k&0x80000000u)?(k^0x80000000u):~k;
  return __uint_as_float(b);
}
__device__ __forceinline__ unsigned long long pk_make(float v,int idx){
  return ((unsigned long long)enc_f(v)<<32)|(unsigned)~(unsigned)idx;
}
__device__ __forceinline__ int pk_idx(unsigned long long p){
  return (int)~(unsigned)(p&0xFFFFFFFFull);
}

// ---------------- init ------------------------------------------------------
__global__ void k_init(){
  int i=blockIdx.x*256+threadIdx.x;
  if (i<B*NJ) g_snearpack[i]=0ull;
  if (i<B*Q*NW*MSP){ g_rowpack[i]=0ull; g_cmax[i]=0u; }
  if (i==0) g_L[0]=0;
}

// ---------------- K1: inverse column norms ---------------------------------
__global__ void k_norms(const float* __restrict__ sup, const float* __restrict__ unl){
  int i=blockIdx.x*256+threadIdx.x;
  if (i<B*MU){
    int b=i/MU, m=i%MU, ui=m/HW, p=m%HW;
    const float* base=unl+((size_t)(b*U+ui)*C)*HW+p;
    float ss=0.f;
    for (int c=0;c<C;c++){ float x=base[(size_t)c*HW]; ss+=x*x; }
    g_rnu[i]=1.f/fmaxf(sqrtf(ss),1e-12f);
  }
  if (i<B*NJ){
    int b=i/NJ, j=i%NJ, n=j/MS, s=j%MS;
    const float* base=sup+((size_t)(b*NW+n)*C)*HW+s;
    float ss=0.f;
    for (int c=0;c<C;c++){ float x=base[(size_t)c*HW]; ss+=x*x; }
    g_rns[i]=1.f/fmaxf(sqrtf(ss),1e-12f);
  }
}

// ---------------- K2: u2s — s_near (col argmax) + u_near/cls (row argmax) ---
__global__ __launch_bounds__(256) void k_u2s(const float* __restrict__ sup, const float* __restrict__ unl){
  int b=blockIdx.x/138;
  int mb=(blockIdx.x%138)*64;
  int tid=threadIdx.x, tm=tid>>4, tl=tid&15;
  int ct=tid&63, rg=tid>>6;
  __shared__ __align__(16) float Ut[4096];
  __shared__ __align__(16) float PS[64*68];   // union: Pt[c][jj] (4096) / St stride 68
  __shared__ unsigned long long colred[256];
  int mv=min(64,MU-mb);
  for (int k=tid;k<4096;k+=256){
    int c=k>>6, mm=k&63, m=mb+mm; float v=0.f;
    if (mm<mv){ int ui=m/HW, p=m%HW; v=unl[((size_t)(b*U+ui)*C+c)*HW+p]*g_rnu[b*MU+m]; }
    Ut[c*64+mm]=v;
  }
  unsigned long long rowpk[4]={0ull,0ull,0ull,0ull};
  for (int jc=0;jc<35;jc++){
    int j0=jc*64, jv=min(64,NJ-j0);
    __syncthreads();
    for (int k=tid;k<4096;k+=256){
      int c=k>>6, jj=k&63, j=j0+jj; float v=0.f;
      if (jj<jv){ int n=j/MS, s=j%MS; v=sup[((size_t)(b*NW+n)*C+c)*HW+s]*g_rns[b*NJ+j]; }
      PS[c*64+jj]=v;
    }
    __syncthreads();
    float s[4][4]={};
    for (int c=0;c<64;c++){
      float a[4],bv[4];
      *(float4*)a=*(const float4*)&Ut[c*64+tm*4];
      *(float4*)bv=*(const float4*)&PS[c*64+tl*4];
      #pragma unroll
      for (int i=0;i<4;i++)
        #pragma unroll
        for (int j=0;j<4;j++) s[i][j]=fmaf(a[i],bv[j],s[i][j]);
    }
    // row-best in registers (mask pad cols)
    #pragma unroll
    for (int i=0;i<4;i++){
      unsigned long long p=rowpk[i];
      #pragma unroll
      for (int j=0;j<4;j++){
        if (tl*4+j<jv){
          unsigned long long c2=pk_make(s[i][j], j0+tl*4+j);
          if (c2>p) p=c2;
        }
      }
      rowpk[i]=p;
    }
    __syncthreads();            // all GEMM reads of PS done before St overwrite
    #pragma unroll
    for (int i=0;i<4;i++) *(float4*)&PS[(tm*4+i)*68+tl*4]=*(float4*)s[i];
    __syncthreads();
    // column-parallel scan: thread -> col ct, rows rg*16..+15
    unsigned long long cpk=0ull;
    if (ct<jv){
      for (int r=0;r<16;r++){
        int mm=rg*16+r;
        if (mm<mv){
          unsigned long long c2=pk_make(PS[mm*68+ct], mb+mm);
          if (c2>cpk) cpk=c2;
        }
      }
    }
    colred[tid]=cpk;
    __syncthreads();
    if (tid<64 && tid<jv){
      unsigned long long p=colred[tid];
      if (colred[64+tid]>p) p=colred[64+tid];
      if (colred[128+tid]>p) p=colred[128+tid];
      if (colred[192+tid]>p) p=colred[192+tid];
      if (p) atomicMax(&g_snearpack[b*NJ+j0+tid],p);
    }
  }
  // finalize row-best: u_near (min-j argmax); cls = bestj/MS (same tie semantics)
  #pragma unroll
  for (int i=0;i<4;i++){
    unsigned long long p=rowpk[i];
    #pragma unroll
    for (int mk=1;mk<16;mk<<=1){ unsigned long long o=__shfl_xor(p,mk); if (o>p) p=o; }
    if (tl==0 && tm*4+i<mv) g_unear[b*MU+mb+tm*4+i]=pk_idx(p);
  }
}

// ---------------- K3: mutual-NN check --------------------------------------
__global__ void k_mutual(){
  int i=blockIdx.x*256+threadIdx.x;
  if (i>=B*MU) return;
  int b=i/MU, m=i%MU;
  int j=g_unear[i];
  int sm_=pk_idx(g_snearpack[b*NJ+j]);
  g_clssel[i]=(sm_==m)?(j/MS):-1;
}

// ---------------- K4: stable compaction per (b,n); counts; L ----------------
__global__ __launch_bounds__(256) void k_compact(){
  int b=blockIdx.x/NW, n=blockIdx.x%NW;
  int tid=threadIdx.x, lane=tid&63, w=tid>>6;
  __shared__ int wtot[4];
  int base=0;
  for (int m0=0;m0<MU;m0+=256){
    int m=m0+tid;
    bool flag=(m<MU)&&(g_clssel[b*MU+m]==n);
    unsigned long long bal=__ballot(flag);
    if (lane==0) wtot[w]=(int)__popcll(bal);
    __syncthreads();
    int wpre=0, tot=0;
    #pragma unroll
    for (int ww=0;ww<4;ww++){ if (ww<w) wpre+=wtot[ww]; tot+=wtot[ww]; }
    if (flag){
      int pre=(int)__popcll(bal&((1ull<<lane)-1ull));
      g_selidx[(b*NW+n)*LCAP+base+wpre+pre]=m;
    }
    base+=tot;
    __syncthreads();
  }
  if (tid==0){ g_counts[b*NW+n]=base; atomicMax(&g_L[0],base); }
}

// ---------------- K5: k_sup / v_sup (zero-filled to LTCAP) ------------------
__global__ __launch_bounds__(64) void k_kv(const float* __restrict__ sup, const float* __restrict__ unl,
                                           const float* __restrict__ kw, const float* __restrict__ vw){
  int blk=blockIdx.x;
  int lb=blk%(LTCAP/64); blk/=(LTCAP/64);
  int n=blk%NW, b=blk/NW;
  int tid=threadIdx.x;
  int l=lb*64+tid;
  int cnt=g_counts[b*NW+n];
  __shared__ float F[4096];
  for (int c=0;c<C;c++){
    float v=0.f;
    if (l<MS) v=sup[((size_t)(b*NW+n)*C+c)*HW+l];
    else if (l<MS+cnt){
      int mg=g_selidx[(b*NW+n)*LCAP+(l-MS)];
      int ui=mg/HW, p=mg%HW;
      v=unl[((size_t)(b*U+ui)*C+c)*HW+p];
    }
    F[c*64+tid]=v;
  }
  size_t ob=((size_t)(b*NW+n)*PD)*LTCAP+l;
  for (int o=0;o<PD;o++){
    float ka=0.f, va=0.f;
    for (int c=0;c<C;c++){ float f=F[c*64+tid]; ka=fmaf(kw[o*C+c],f,ka); va=fmaf(vw[o*C+c],f,va); }
    g_ksup[ob+(size_t)o*LTCAP]=ka;
    g_vsup[ob+(size_t)o*LTCAP]=va;
  }
}

// ---------------- K5b: normalized vbar = mean_l v_sup, L2-normalized --------
__global__ __launch_bounds__(64) void k_vbar(){
  int bn=blockIdx.x;            // 0..B*NW-1
  int o=threadIdx.x;
  int cnt=g_counts[bn];
  int Lt=MS+g_L[0];
  const float* row=&g_vsup[((size_t)bn*PD+o)*LTCAP];
  float s=0.f;
  for (int l=0;l<MS+cnt;l++) s+=row[l];
  float vb=s/(float)Lt;
  float ss=vb*vb;
  #pragma unroll
  for (int mk=1;mk<64;mk<<=1) ss+=__shfl_xor(ss,mk);
  g_vbarn[bn*PD+o]=vb/(sqrtf(ss)+1e-16f);
}

// ---------------- K6: q_proj / normalized v_query (stride MSP, zero pad) ----
__global__ __launch_bounds__(64) void k_qproj(const float* __restrict__ qx, const float* __restrict__ qw,
                                              const float* __restrict__ vw){
  int blk=blockIdx.x;
  int mt=blk%7; blk/=7;
  int bq=blk;
  int tid=threadIdx.x, m=mt*64+tid;
  __shared__ float F[4096];
  size_t ob=((size_t)bq*PD)*MSP+m;
  if (m>=MS){
    for (int o=0;o<PD;o++){ g_qproj[ob+(size_t)o*MSP]=0.f; g_vqn[ob+(size_t)o*MSP]=0.f; }
    return;
  }
  for (int c=0;c<C;c++) F[c*64+tid]=qx[((size_t)bq*C+c)*HW+m];
  float ss=0.f;
  for (int o=0;o<PD;o++){
    float qa=0.f, va=0.f;
    for (int c=0;c<C;c++){ float f=F[c*64+tid]; qa=fmaf(qw[o*C+c],f,qa); va=fmaf(vw[o*C+c],f,va); }
    g_qproj[ob+(size_t)o*MSP]=qa;
    g_vqn[ob+(size_t)o*MSP]=va;
    ss=fmaf(va,va,ss);
  }
  float rn=1.f/(sqrtf(ss)+1e-16f);
  for (int o=0;o<PD;o++) g_vqn[ob+(size_t)o*MSP]*=rn;
}

// ---------------- K7: pass A — full simi; row-best (q_near) + col-best ------
__global__ __launch_bounds__(256) void k_passA(){
  int blk=blockIdx.x;
  int lcg=blk%11; blk/=11;
  int n=blk%NW; blk/=NW;
  int bq=blk; int b=bq/Q;
  int Lt=MS+g_L[0];
  int nch=(Lt+63)>>6;
  int lc0=lcg*4;
  if (lc0>=nch) return;
  int lc1=min(lc0+4,nch);
  int tid=threadIdx.x, tm=tid>>4, tl=tid&15;
  int ct=tid&63, rg=tid>>6;
  int bqn=bq*NW+n;
  __shared__ __align__(16) float Kt[4096];
  __shared__ __align__(16) float QS[64*68];   // union: Qt[o][m](4096) / St stride 68
  __shared__ unsigned long long colred[256];
  __shared__ unsigned long long rowpk[MSP];
  for (int i=tid;i<MSP;i+=256) rowpk[i]=0ull;
  const size_t qb=(size_t)bq*PD*MSP;
  const size_t kb=(size_t)(b*NW+n)*PD*LTCAP;
  for (int lc=lc0;lc<lc1;lc++){
    int l0=lc<<6, lv=min(64,Lt-l0);
    __syncthreads();
    for (int k=tid;k<1024;k+=256){
      int o=k>>4, lq=k&15;
      *(float4*)&Kt[o*64+lq*4]=*(const float4*)&g_ksup[kb+(size_t)o*LTCAP+l0+lq*4];
    }
    unsigned long long cpk=0ull;
    for (int mt=0;mt<7;mt++){
      __syncthreads();
      for (int k=tid;k<1024;k+=256){
        int o=k>>4, mq=k&15;
        *(float4*)&QS[o*64+mq*4]=*(const float4*)&g_qproj[qb+(size_t)o*MSP+mt*64+mq*4];
      }
      __syncthreads();
      float s[4][4]={};
      for (int c=0;c<64;c++){
        float a[4],bv[4];
        *(float4*)a=*(const float4*)&QS[c*64+tm*4];
        *(float4*)bv=*(const float4*)&Kt[c*64+tl*4];
        #pragma unroll
        for (int i=0;i<4;i++)
          #pragma unroll
          for (int j=0;j<4;j++) s[i][j]=fmaf(a[i],bv[j],s[i][j]);
      }
      #pragma unroll
      for (int i=0;i<4;i++)
        #pragma unroll
        for (int j=0;j<4;j++) s[i][j]*=0.125f;
      // row-best in regs + shuffle over tl group
      int mbase=mt*64+tm*4;
      #pragma unroll
      for (int i=0;i<4;i++){
        if (mbase+i<MS){
          unsigned long long p=0ull;
          #pragma unroll
          for (int j=0;j<4;j++){
            if (tl*4+j<lv){
              unsigned long long c2=pk_make(s[i][j], l0+tl*4+j);
              if (c2>p) p=c2;
            }
          }
          #pragma unroll
          for (int mk=1;mk<16;mk<<=1){ unsigned long long o=__shfl_xor(p,mk); if (o>p) p=o; }
          if (tl==0 && p>rowpk[mbase+i]) rowpk[mbase+i]=p;
        }
      }
      __syncthreads();           // GEMM reads of QS done before St overwrite
      #pragma unroll
      for (int i=0;i<4;i++) *(float4*)&QS[(tm*4+i)*68+tl*4]=*(float4*)s[i];
      __syncthreads();
      if (ct<lv){
        for (int r=0;r<16;r++){
          int m=mt*64+rg*16+r;
          if (m<MS){
            unsigned long long c2=pk_make(QS[(rg*16+r)*68+ct], m);
            if (c2>cpk) cpk=c2;
          }
        }
      }
    } // mt
    __syncthreads();
    colred[tid]=cpk;
    __syncthreads();
    if (tid<64 && tid<lv){
      unsigned long long p=colred[tid];
      if (colred[64+tid]>p) p=colred[64+tid];
      if (colred[128+tid]>p) p=colred[128+tid];
      if (colred[192+tid]>p) p=colred[192+tid];
      g_snear2[(size_t)bqn*LTCAP+l0+tid]=pk_idx(p);
    }
  } // lc
  __syncthreads();
  for (int m=tid;m<MS;m+=256){
    unsigned long long p=rowpk[m];
    if (p) atomicMax(&g_rowpack[(size_t)bqn*MSP+m],p);
  }
}

// ---------------- K8: q_mask + masked-row compaction ------------------------
__global__ __launch_bounds__(256) void k_qmask(){
  int bq=blockIdx.x;
  int tid=threadIdx.x, lane=tid&63, w=tid>>6;
  __shared__ int wtot[4];
  int base=0;
  for (int m0=0;m0<MS;m0+=256){
    int m=m0+tid;
    bool qm=false;
    if (m<MS){
      unsigned bhv=0u; unsigned long long bp=0ull; int bn=0;
      #pragma unroll
      for (int n=0;n<NW;n++){
        unsigned long long pk=g_rowpack[(size_t)(bq*NW+n)*MSP+m];
        unsigned hv=(unsigned)(pk>>32);
        if (hv>bhv){bhv=hv;bp=pk;bn=n;}
      }
      int bl=pk_idx(bp);
      qm=(g_snear2[(size_t)(bq*NW+bn)*LTCAP+bl]==m);
    }
    unsigned long long bal=__ballot(qm);
    if (lane==0) wtot[w]=(int)__popcll(bal);
    __syncthreads();
    int wpre=0, tot=0;
    #pragma unroll
    for (int ww=0;ww<4;ww++){ if (ww<w) wpre+=wtot[ww]; tot+=wtot[ww]; }
    if (qm){
      int pre=(int)__popcll(bal&((1ull<<lane)-1ull));
      g_qmrows[bq*MSP+base+wpre+pre]=m;
    }
    base+=tot;
    __syncthreads();
  }
  if (tid==0) g_qmcount[bq]=base;
}

// ---------------- K9: pass B — masked rows only: softmax+PV+normalize+simi2 -
__global__ __launch_bounds__(256) void k_passB(){
  int blk=blockIdx.x;
  int rt=blk%7; blk/=7;
  int n=blk%NW; blk/=NW;
  int bq=blk; int b=bq/Q;
  int nm=g_qmcount[bq];
  if (rt*64>=nm) return;
  int bqn=bq*NW+n;
  int Lt=MS+g_L[0];
  int nch=(Lt+63)>>6;
  int tid=threadIdx.x, tm=tid>>4, tl=tid&15;
  __shared__ __align__(16) float Qt[4096];
  __shared__ __align__(16) float KV[64*66];   // union: Kt[o][l](4096) / Vt[l*66+o]
  __shared__ __align__(16) float Pt[64*65];   // P / aligned rows, stride 65
  __shared__ int rows_s[64];
  if (tid<64){ int g=rt*64+tid; rows_s[tid]=(g<nm)?g_qmrows[bq*MSP+g]:0; }
  __syncthreads();
  const size_t qb=(size_t)bq*PD*MSP;
  const size_t kb=(size_t)(b*NW+n)*PD*LTCAP;
  for (int k=tid;k<4096;k+=256){
    int o=k>>6, rr=k&63;
    Qt[k]=(rt*64+rr<nm)?g_qproj[qb+(size_t)o*MSP+rows_s[rr]]:0.f;
  }
  float m_run[4], l_run[4], acc[4][4]={};
  #pragma unroll
  for (int i=0;i<4;i++){ m_run[i]=NEGF; l_run[i]=0.f; }
  for (int lc=0;lc<nch;lc++){
    int l0=lc<<6, lv=min(64,Lt-l0);
    __syncthreads();
    for (int k=tid;k<1024;k+=256){
      int o=k>>4, lq=k&15;
      *(float4*)&KV[o*64+lq*4]=*(const float4*)&g_ksup[kb+(size_t)o*LTCAP+l0+lq*4];
    }
    __syncthreads();
    float s[4][4]={};
    for (int c=0;c<64;c++){
      float a[4],bv[4];
      *(float4*)a=*(const float4*)&Qt[c*64+tm*4];
      *(float4*)bv=*(const float4*)&KV[c*64+tl*4];
      #pragma unroll
      for (int i=0;i<4;i++)
        #pragma unroll
        for (int j=0;j<4;j++) s[i][j]=fmaf(a[i],bv[j],s[i][j]);
    }
    #pragma unroll
    for (int i=0;i<4;i++)
      #pragma unroll
      for (int j=0;j<4;j++) s[i][j]=(tl*4+j<lv)?s[i][j]*0.125f:NEGF;
    // online softmax per row (shuffle over 16-lane tl group)
    #pragma unroll
    for (int i=0;i<4;i++){
      float mx=fmaxf(fmaxf(s[i][0],s[i][1]),fmaxf(s[i][2],s[i][3]));
      #pragma unroll
      for (int mk=1;mk<16;mk<<=1) mx=fmaxf(mx,__shfl_xor(mx,mk));
      float nm2=fmaxf(m_run[i],mx);
      float al=(m_run[i]<-1e37f)?0.f:__expf(m_run[i]-nm2);
      float ps=0.f;
      #pragma unroll
      for (int j=0;j<4;j++){
        float e=(s[i][j]<-1e37f)?0.f:__expf(s[i][j]-nm2);
        s[i][j]=e; ps+=e;
      }
      #pragma unroll
      for (int mk=1;mk<16;mk<<=1) ps+=__shfl_xor(ps,mk);
      l_run[i]=l_run[i]*al+ps; m_run[i]=nm2;
      #pragma unroll
      for (int j=0;j<4;j++) acc[i][j]*=al;
    }
    __syncthreads();             // K reads + prev PV Pt reads done
    #pragma unroll
    for (int i=0;i<4;i++)
      #pragma unroll
      for (int j=0;j<4;j++) Pt[(tm*4+i)*65+tl*4+j]=s[i][j];
    for (int k=tid;k<4096;k+=256){
      int o=k>>6, ll=k&63;
      KV[ll*66+o]=g_vsup[kb+(size_t)o*LTCAP+l0+ll];
    }
    __syncthreads();
    for (int l4=0;l4<64;l4+=4){
      float p[4][4];
      #pragma unroll
      for (int i=0;i<4;i++)
        #pragma unroll
        for (int u=0;u<4;u++) p[i][u]=Pt[(tm*4+i)*65+l4+u];
      #pragma unroll
      for (int u=0;u<4;u++){
        float2 v01=*(const float2*)&KV[(l4+u)*66+tl*4];
        float2 v23=*(const float2*)&KV[(l4+u)*66+tl*4+2];
        #pragma unroll
        for (int i=0;i<4;i++){
          acc[i][0]=fmaf(p[i][u],v01.x,acc[i][0]);
          acc[i][1]=fmaf(p[i][u],v01.y,acc[i][1]);
          acc[i][2]=fmaf(p[i][u],v23.x,acc[i][2]);
          acc[i][3]=fmaf(p[i][u],v23.y,acc[i][3]);
        }
      }
    }
  } // lc
  // epilogue: aligned = acc/l_run; row norms via shuffle; simi2 max
  float rn[4];
  #pragma unroll
  for (int i=0;i<4;i++){
    float ss=0.f;
    #pragma unroll
    for (int j=0;j<4;j++){ acc[i][j]/=l_run[i]; ss=fmaf(acc[i][j],acc[i][j],ss); }
    #pragma unroll
    for (int mk=1;mk<16;mk<<=1) ss+=__shfl_xor(ss,mk);
    rn[i]=1.f/(sqrtf(ss)+1e-16f);
  }
  __syncthreads();
  #pragma unroll
  for (int i=0;i<4;i++)
    #pragma unroll
    for (int j=0;j<4;j++) Pt[(tm*4+i)*65+tl*4+j]=acc[i][j];
  int rowok[4];
  #pragma unroll
  for (int i=0;i<4;i++) rowok[i]=(rt*64+tm*4+i<nm);
  for (int kt=0;kt<7;kt++){
    __syncthreads();
    for (int k=tid;k<1024;k+=256){
      int o=k>>4, kq=k&15;
      *(float4*)&KV[o*64+kq*4]=*(const float4*)&g_vqn[qb+(size_t)o*MSP+kt*64+kq*4];
    }
    __syncthreads();
    float d[4][4]={};
    for (int o=0;o<64;o++){
      float a[4], bv4[4];
      #pragma unroll
      for (int i=0;i<4;i++) a[i]=Pt[(tm*4+i)*65+o];
      *(float4*)bv4=*(const float4*)&KV[o*64+tl*4];
      #pragma unroll
      for (int i=0;i<4;i++)
        #pragma unroll
        for (int j=0;j<4;j++) d[i][j]=fmaf(a[i],bv4[j],d[i][j]);
    }
    #pragma unroll
    for (int j=0;j<4;j++){
      int kg=kt*64+tl*4+j;
      float mv=NEGF;
      #pragma unroll
      for (int i=0;i<4;i++) if (rowok[i]) mv=fmaxf(mv,d[i][j]*rn[i]);
      mv=fmaxf(mv,__shfl_xor(mv,16));
      mv=fmaxf(mv,__shfl_xor(mv,32));
      if (((tid>>4)&3)==0 && kg<MS && mv>-1e37f)
        atomicMax(&g_cmax[(size_t)bqn*MSP+kg],enc_f(mv));
    }
  }
}

// ---------------- K9b: vbar row contribution (covers all q_mask=0 rows) -----
__global__ __launch_bounds__(448) void k_vbarsim(){
  int bqn=blockIdx.x;
  int n=bqn%NW, bq=bqn/NW, b=bq/Q;
  if (g_qmcount[bq]>=MS) return;
  int k=threadIdx.x;
  if (k>=MS) return;
  const float* vb=&g_vbarn[(b*NW+n)*PD];
  const float* vq=&g_vqn[(size_t)bq*PD*MSP+k];
  float d=0.f;
  for (int o=0;o<PD;o++) d=fmaf(vb[o],vq[(size_t)o*MSP],d);
  atomicMax(&g_cmax[(size_t)bqn*MSP+k],enc_f(d));
}

// ---------------- K10: logits ------------------------------------------------
__global__ __launch_bounds__(256) void k_logits(){
  int bqn=blockIdx.x;
  __shared__ float red[256];
  float p=0.f;
  for (int k=threadIdx.x;k<MS;k+=256){
    float v=dec_f(g_cmax[(size_t)bqn*MSP+k]);
    p+=(v+1.f)*0.5f;
  }
  red[threadIdx.x]=p; __syncthreads();
  for (int s=128;s;s>>=1){ if (threadIdx.x<s) red[threadIdx.x]+=red[threadIdx.x+s]; __syncthreads(); }
  if (threadIdx.x==0) g_logits[bqn]=red[0];
}

// ---------------- K11: NLL loss ---------------------------------------------
__global__ void k_loss(const int* __restrict__ qy, float* __restrict__ out){
  int t=threadIdx.x;
  float lp=0.f;
  if (t<B*Q){
    int y=qy[t];
    float xv[NW]; float mxv=NEGF;
    #pragma unroll
    for (int n=0;n<NW;n++){ xv[n]=g_logits[t*NW+n]*5.f; mxv=fmaxf(mxv,xv[n]); }
    float s=0.f, xy=0.f;
    #pragma unroll
    for (int n=0;n<NW;n++){ s+=__expf(xv[n]-mxv); if (n==y) xy=xv[n]; }
    lp=xy-mxv-logf(s);
  }
  #pragma unroll
  for (int off=32;off;off>>=1) lp+=__shfl_down(lp,off);
  if (t==0) out[0]=-lp/(float)(B*Q);
}

extern "C" void kernel_launch(void* const* d_in, const int* in_sizes, int n_in,
                              void* d_out, int out_size, void* d_ws, size_t ws_size,
                              hipStream_t stream) {
  (void)in_sizes; (void)n_in; (void)out_size; (void)d_ws; (void)ws_size;
  const float* sup=(const float*)d_in[0];
  const float* qx =(const float*)d_in[2];
  const int*   qy =(const int*)d_in[3];
  const float* unl=(const float*)d_in[4];
  const float* kw =(const float*)d_in[5];
  const float* qw =(const float*)d_in[6];
  const float* vw =(const float*)d_in[7];
  float* out=(float*)d_out;

  k_init   <<<263,256,0,stream>>>();
  k_norms  <<<69,256,0,stream>>>(sup,unl);
  k_u2s    <<<B*138,256,0,stream>>>(sup,unl);
  k_mutual <<<69,256,0,stream>>>();
  k_compact<<<B*NW,256,0,stream>>>();
  k_kv     <<<B*NW*(LTCAP/64),64,0,stream>>>(sup,unl,kw,vw);
  k_vbar   <<<B*NW,64,0,stream>>>();
  k_qproj  <<<B*Q*7,64,0,stream>>>(qx,qw,vw);
  k_passA  <<<B*Q*NW*11,256,0,stream>>>();
  k_qmask  <<<B*Q,256,0,stream>>>();
  k_passB  <<<B*Q*NW*7,256,0,stream>>>();
  k_vbarsim<<<B*Q*NW,448,0,stream>>>();
  k_logits <<<B*Q*NW,256,0,stream>>>();
  k_loss   <<<1,64,0,stream>>>(qy,out);
}

// Round 3
// 873.468 us; speedup vs baseline: 2.2232x; 1.2948x over previous
//
#include <hip/hip_runtime.h>
#include <math.h>

#define B 2
#define Q 15
#define U 20
#define C 64
#define HW 441
#define NW 5
#define MU (U*HW)      // 8820
#define MS HW          // 441
#define NJ (NW*MS)     // 2205
#define PD 64
#define LCAP NJ
#define LTCAP 2688     // 42*64 >= 441+2205
#define MSP 448
#define NEGF (-3.402823466e38f)

// ---------------- device scratch (rewritten every call before any read) -----
__device__ float g_rnu[B*MU];
__device__ float g_rns[B*NJ];
__device__ unsigned long long g_snearpack[B*NJ];
__device__ unsigned long long g_unearpack[B*MU];
__device__ int   g_counts[B*NW];
__device__ int   g_L[1];
__device__ int   g_selidx[B*NW*LCAP];
__device__ float g_ksup[(size_t)B*NW*PD*LTCAP];
__device__ float g_vsup[(size_t)B*NW*PD*LTCAP];
__device__ float g_vbarn[B*NW*PD];
__device__ float g_qproj[(size_t)B*Q*PD*MSP];
__device__ float g_vqn[(size_t)B*Q*PD*MSP];
__device__ unsigned long long g_rowpack[(size_t)B*Q*NW*MSP];
__device__ int   g_snear2[(size_t)B*Q*NW*LTCAP];
__device__ int   g_qmrows[B*Q*MSP];
__device__ int   g_qmcount[B*Q];
__device__ unsigned g_cmax[(size_t)B*Q*NW*MSP];
__device__ float g_logits[B*Q*NW];

__device__ __forceinline__ unsigned enc_f(float f){
  unsigned b=__float_as_uint(f);
  return (b&0x80000000u)? ~b : (b|0x80000000u);
}
__device__ __forceinline__ float dec_f(unsigned k){
  unsigned b=(k&0x80000000u)?(k^0x80000000u):~k;
  return __uint_as_float(b);
}
__device__ __forceinline__ unsigned long long pk_make(float v,int idx){
  return ((unsigned long long)enc_f(v)<<32)|(unsigned)~(unsigned)idx;
}
__device__ __forceinline__ int pk_idx(unsigned long long p){
  return (int)~(unsigned)(p&0xFFFFFFFFull);
}

// ---------------- init ------------------------------------------------------
__global__ void k_init(){
  int i=blockIdx.x*256+threadIdx.x;
  if (i<B*NJ) g_snearpack[i]=0ull;
  if (i<B*MU) g_unearpack[i]=0ull;
  if (i<B*Q*NW*MSP){ g_rowpack[i]=0ull; g_cmax[i]=0u; }
  if (i==0) g_L[0]=0;
}

// ---------------- K1: inverse column norms ---------------------------------
__global__ void k_norms(const float* __restrict__ sup, const float* __restrict__ unl){
  int i=blockIdx.x*256+threadIdx.x;
  if (i<B*MU){
    int b=i/MU, m=i%MU, ui=m/HW, p=m%HW;
    const float* base=unl+((size_t)(b*U+ui)*C)*HW+p;
    float ss=0.f;
    for (int c=0;c<C;c++){ float x=base[(size_t)c*HW]; ss+=x*x; }
    g_rnu[i]=1.f/fmaxf(sqrtf(ss),1e-12f);
  }
  if (i<B*NJ){
    int b=i/NJ, j=i%NJ, n=j/MS, s=j%MS;
    const float* base=sup+((size_t)(b*NW+n)*C)*HW+s;
    float ss=0.f;
    for (int c=0;c<C;c++){ float x=base[(size_t)c*HW]; ss+=x*x; }
    g_rns[i]=1.f/fmaxf(sqrtf(ss),1e-12f);
  }
}

// ---------------- K2: u2s — col-split 6x; 64x128 tiles; shuffle argmaxes ----
// block = (b, row-block of 64, col-group of 3x128)
__global__ __launch_bounds__(256) void k_u2s(const float* __restrict__ sup, const float* __restrict__ unl){
  int blk=blockIdx.x;
  int grp=blk%6; blk/=6;
  int rb=blk%138; int b=blk/138;
  int mb=rb*64;
  int tid=threadIdx.x, tm=tid>>4, tl=tid&15;
  int lane=tid&63, w=tid>>6;
  __shared__ __align__(16) float Ut[4096];     // [c][m] 16KB
  __shared__ __align__(16) float Pt[8192];     // [c][j] 32KB
  __shared__ unsigned long long colred[512];   // [w][128] 4KB
  int mv=min(64,MU-mb);
  for (int k=tid;k<4096;k+=256){
    int c=k>>6, mm=k&63; float v=0.f;
    if (mm<mv){ int m=mb+mm, ui=m/HW, p=m%HW; v=unl[((size_t)(b*U+ui)*C+c)*HW+p]*g_rnu[b*MU+m]; }
    Ut[c*64+mm]=v;
  }
  unsigned long long rowpk[4]={0ull,0ull,0ull,0ull};
  for (int t=0;t<3;t++){
    int j0=(grp*3+t)*128;
    int jv=min(128,NJ-j0);
    __syncthreads();
    for (int k=tid;k<8192;k+=256){
      int c=k>>7, jj=k&127; float v=0.f;
      if (jj<jv){ int j=j0+jj, n=j/MS, s=j%MS; v=sup[((size_t)(b*NW+n)*C+c)*HW+s]*g_rns[b*NJ+j]; }
      Pt[c*128+jj]=v;
    }
    __syncthreads();
    float s[4][8]={};
    for (int c=0;c<64;c++){
      float a[4],b0[4],b1[4];
      *(float4*)a =*(const float4*)&Ut[c*64+tm*4];
      *(float4*)b0=*(const float4*)&Pt[c*128+tl*4];
      *(float4*)b1=*(const float4*)&Pt[c*128+64+tl*4];
      #pragma unroll
      for (int i=0;i<4;i++)
        #pragma unroll
        for (int j=0;j<4;j++){ s[i][j]=fmaf(a[i],b0[j],s[i][j]); s[i][j+4]=fmaf(a[i],b1[j],s[i][j+4]); }
    }
    // row-best (argmax over j) into registers
    #pragma unroll
    for (int i=0;i<4;i++){
      if (tm*4+i<mv){
        unsigned long long p=rowpk[i];
        #pragma unroll
        for (int j=0;j<8;j++){
          int jj=(j<4)?(tl*4+j):(64+tl*4+(j-4));
          if (jj<jv){
            unsigned long long c2=pk_make(s[i][j],j0+jj);
            if (c2>p) p=c2;
          }
        }
        rowpk[i]=p;
      }
    }
    // col-best (argmax over m): pack 4 rows, reduce over tm
    unsigned long long cpk[8];
    #pragma unroll
    for (int j=0;j<8;j++){
      unsigned long long p=0ull;
      #pragma unroll
      for (int i=0;i<4;i++){
        if (tm*4+i<mv){
          unsigned long long c2=pk_make(s[i][j],mb+tm*4+i);
          if (c2>p) p=c2;
        }
      }
      cpk[j]=p;
    }
    #pragma unroll
    for (int j=0;j<8;j++){
      unsigned long long o;
      o=__shfl_xor(cpk[j],16); if (o>cpk[j]) cpk[j]=o;
      o=__shfl_xor(cpk[j],32); if (o>cpk[j]) cpk[j]=o;
    }
    if ((lane>>4)==0){
      #pragma unroll
      for (int j=0;j<8;j++){
        int jj=(j<4)?(tl*4+j):(64+tl*4+(j-4));
        colred[w*128+jj]=cpk[j];
      }
    }
    __syncthreads();
    if (tid<128 && tid<jv){
      unsigned long long p=colred[tid];
      if (colred[128+tid]>p) p=colred[128+tid];
      if (colred[256+tid]>p) p=colred[256+tid];
      if (colred[384+tid]>p) p=colred[384+tid];
      if (p) atomicMax(&g_snearpack[b*NJ+j0+tid],p);
    }
  }
  // row-best final: reduce over tl, combine across col-groups via atomic
  #pragma unroll
  for (int i=0;i<4;i++){
    unsigned long long p=rowpk[i];
    #pragma unroll
    for (int mk=1;mk<16;mk<<=1){ unsigned long long o=__shfl_xor(p,mk); if (o>p) p=o; }
    if (tl==0 && tm*4+i<mv && p) atomicMax(&g_unearpack[b*MU+mb+tm*4+i],p);
  }
}

// ---------------- K4: mutual check + stable compaction; counts; L ----------
__global__ __launch_bounds__(256) void k_compact(){
  int b=blockIdx.x/NW, n=blockIdx.x%NW;
  int tid=threadIdx.x, lane=tid&63, w=tid>>6;
  __shared__ int wtot[4];
  int base=0;
  for (int m0=0;m0<MU;m0+=256){
    int m=m0+tid;
    bool flag=false;
    if (m<MU){
      int j=pk_idx(g_unearpack[b*MU+m]);
      flag=(j/MS==n) && (pk_idx(g_snearpack[b*NJ+j])==m);
    }
    unsigned long long bal=__ballot(flag);
    if (lane==0) wtot[w]=(int)__popcll(bal);
    __syncthreads();
    int wpre=0, tot=0;
    #pragma unroll
    for (int ww=0;ww<4;ww++){ if (ww<w) wpre+=wtot[ww]; tot+=wtot[ww]; }
    if (flag){
      int pre=(int)__popcll(bal&((1ull<<lane)-1ull));
      g_selidx[(b*NW+n)*LCAP+base+wpre+pre]=m;
    }
    base+=tot;
    __syncthreads();
  }
  if (tid==0){ g_counts[b*NW+n]=base; atomicMax(&g_L[0],base); }
}

// ---------------- K5: k_sup / v_sup (zero-filled to Lt; 256 thr, o-split) ---
__global__ __launch_bounds__(256) void k_kv(const float* __restrict__ sup, const float* __restrict__ unl,
                                            const float* __restrict__ kw, const float* __restrict__ vw){
  int blk=blockIdx.x;
  int lb=blk%(LTCAP/64); blk/=(LTCAP/64);
  int n=blk%NW, b=blk/NW;
  int Lt=MS+g_L[0];
  if (lb*64>=Lt) return;
  int cnt=g_counts[b*NW+n];
  int tid=threadIdx.x, lane=tid&63, w=tid>>6;
  __shared__ float F[4096];
  __shared__ const float* ptr_s[64];
  if (tid<64){
    int l=lb*64+tid;
    const float* p=nullptr;
    if (l<MS) p=&sup[((size_t)(b*NW+n)*C)*HW+l];
    else if (l<MS+cnt){
      int mg=g_selidx[(b*NW+n)*LCAP+(l-MS)];
      int ui=mg/HW, pp=mg%HW;
      p=&unl[((size_t)(b*U+ui)*C)*HW+pp];
    }
    ptr_s[tid]=p;
  }
  __syncthreads();
  for (int k=tid;k<4096;k+=256){
    int c=k>>6, ll=k&63;
    const float* p=ptr_s[ll];
    F[c*64+ll]=p?p[(size_t)c*HW]:0.f;
  }
  __syncthreads();
  int l=lb*64+lane;
  size_t ob=((size_t)(b*NW+n)*PD)*LTCAP+l;
  for (int oo=0;oo<16;oo++){
    int o=w*16+oo;
    float ka=0.f, va=0.f;
    for (int c=0;c<C;c++){ float f=F[c*64+lane]; ka=fmaf(kw[o*C+c],f,ka); va=fmaf(vw[o*C+c],f,va); }
    g_ksup[ob+(size_t)o*LTCAP]=ka;
    g_vsup[ob+(size_t)o*LTCAP]=va;
  }
}

// ---------------- K5b: normalized vbar = mean_l v_sup, L2-normalized --------
__global__ __launch_bounds__(256) void k_vbar(){
  int bn=blockIdx.x;
  int tid=threadIdx.x, lane=tid&63, w=tid>>6;
  int cnt=g_counts[bn];
  int Lt=MS+g_L[0];
  __shared__ float vb_s[64];
  for (int oo=0;oo<16;oo++){
    int o=w*16+oo;
    const float* row=&g_vsup[((size_t)bn*PD+o)*LTCAP];
    float s=0.f;
    for (int l=lane;l<MS+cnt;l+=64) s+=row[l];
    #pragma unroll
    for (int mk=1;mk<64;mk<<=1) s+=__shfl_xor(s,mk);
    if (lane==0) vb_s[o]=s/(float)Lt;
  }
  __syncthreads();
  if (tid<64){
    float v=vb_s[tid];
    float ss=v*v;
    #pragma unroll
    for (int mk=1;mk<64;mk<<=1) ss+=__shfl_xor(ss,mk);
    g_vbarn[bn*PD+tid]=v/(sqrtf(ss)+1e-16f);
  }
}

// ---------------- K6: q_proj / normalized v_query (256 thr, o-split) --------
__global__ __launch_bounds__(256) void k_qproj(const float* __restrict__ qx, const float* __restrict__ qw,
                                               const float* __restrict__ vw){
  int blk=blockIdx.x;
  int mt=blk%7; blk/=7;
  int bq=blk;
  int tid=threadIdx.x, lane=tid&63, w=tid>>6;
  __shared__ float F[4096];
  __shared__ float ssp[256];
  for (int k=tid;k<4096;k+=256){
    int c=k>>6, mm=k&63, m=mt*64+mm;
    F[c*64+mm]=(m<MS)?qx[((size_t)bq*C+c)*HW+m]:0.f;
  }
  __syncthreads();
  int m=mt*64+lane;
  size_t ob=(size_t)bq*PD*MSP+m;
  float va[16]; float ssl=0.f;
  for (int oo=0;oo<16;oo++){
    int o=w*16+oo;
    float qa=0.f, v=0.f;
    for (int c=0;c<C;c++){ float f=F[c*64+lane]; qa=fmaf(qw[o*C+c],f,qa); v=fmaf(vw[o*C+c],f,v); }
    g_qproj[ob+(size_t)o*MSP]=qa;
    va[oo]=v; ssl=fmaf(v,v,ssl);
  }
  ssp[tid]=ssl;
  __syncthreads();
  float ss=ssp[lane]+ssp[64+lane]+ssp[128+lane]+ssp[192+lane];
  float rn=1.f/(sqrtf(ss)+1e-16f);
  for (int oo=0;oo<16;oo++) g_vqn[ob+(size_t)(w*16+oo)*MSP]=va[oo]*rn;
}

// ---------------- K7: pass A — shuffle-based row/col argmax -----------------
__global__ __launch_bounds__(256) void k_passA(){
  int blk=blockIdx.x;
  int lcg=blk%11; blk/=11;
  int n=blk%NW; blk/=NW;
  int bq=blk; int b=bq/Q;
  int Lt=MS+g_L[0];
  int nch=(Lt+63)>>6;
  int lc0=lcg*4;
  if (lc0>=nch) return;
  int lc1=min(lc0+4,nch);
  int tid=threadIdx.x, tm=tid>>4, tl=tid&15;
  int lane=tid&63, w=tid>>6;
  int bqn=bq*NW+n;
  __shared__ __align__(16) float Kt[4096];
  __shared__ __align__(16) float Qt[4096];
  __shared__ unsigned long long colred[256];   // [w][64]
  __shared__ unsigned long long rowpk[MSP];
  for (int i=tid;i<MSP;i+=256) rowpk[i]=0ull;
  const size_t qb=(size_t)bq*PD*MSP;
  const size_t kb=(size_t)(b*NW+n)*PD*LTCAP;
  for (int lc=lc0;lc<lc1;lc++){
    int l0=lc<<6, lv=min(64,Lt-l0);
    __syncthreads();
    for (int k=tid;k<1024;k+=256){
      int o=k>>4, lq=k&15;
      *(float4*)&Kt[o*64+lq*4]=*(const float4*)&g_ksup[kb+(size_t)o*LTCAP+l0+lq*4];
    }
    unsigned long long cpk[4]={0ull,0ull,0ull,0ull};
    for (int mt=0;mt<7;mt++){
      __syncthreads();
      for (int k=tid;k<1024;k+=256){
        int o=k>>4, mq=k&15;
        *(float4*)&Qt[o*64+mq*4]=*(const float4*)&g_qproj[qb+(size_t)o*MSP+mt*64+mq*4];
      }
      __syncthreads();
      float s[4][4]={};
      for (int c=0;c<64;c++){
        float a[4],bv[4];
        *(float4*)a =*(const float4*)&Qt[c*64+tm*4];
        *(float4*)bv=*(const float4*)&Kt[c*64+tl*4];
        #pragma unroll
        for (int i=0;i<4;i++)
          #pragma unroll
          for (int j=0;j<4;j++) s[i][j]=fmaf(a[i],bv[j],s[i][j]);
      }
      #pragma unroll
      for (int i=0;i<4;i++)
        #pragma unroll
        for (int j=0;j<4;j++) s[i][j]*=0.125f;
      int mbase=mt*64+tm*4;
      // row-best over l (this chunk) -> rowpk LDS (single writer per row)
      #pragma unroll
      for (int i=0;i<4;i++){
        if (mbase+i<MS){
          unsigned long long p=0ull;
          #pragma unroll
          for (int j=0;j<4;j++){
            if (tl*4+j<lv){
              unsigned long long c2=pk_make(s[i][j],l0+tl*4+j);
              if (c2>p) p=c2;
            }
          }
          #pragma unroll
          for (int mk=1;mk<16;mk<<=1){ unsigned long long o=__shfl_xor(p,mk); if (o>p) p=o; }
          if (tl==0 && p>rowpk[mbase+i]) rowpk[mbase+i]=p;
        }
      }
      // col-best over m: accumulate in registers across mt tiles
      #pragma unroll
      for (int j=0;j<4;j++){
        if (tl*4+j<lv){
          unsigned long long p=cpk[j];
          #pragma unroll
          for (int i=0;i<4;i++){
            if (mbase+i<MS){
              unsigned long long c2=pk_make(s[i][j],mbase+i);
              if (c2>p) p=c2;
            }
          }
          cpk[j]=p;
        }
      }
    } // mt
    #pragma unroll
    for (int j=0;j<4;j++){
      unsigned long long o;
      o=__shfl_xor(cpk[j],16); if (o>cpk[j]) cpk[j]=o;
      o=__shfl_xor(cpk[j],32); if (o>cpk[j]) cpk[j]=o;
    }
    if ((lane>>4)==0){
      #pragma unroll
      for (int j=0;j<4;j++) colred[w*64+tl*4+j]=cpk[j];
    }
    __syncthreads();
    if (tid<64 && tid<lv){
      unsigned long long p=colred[tid];
      if (colred[64+tid]>p) p=colred[64+tid];
      if (colred[128+tid]>p) p=colred[128+tid];
      if (colred[192+tid]>p) p=colred[192+tid];
      g_snear2[(size_t)bqn*LTCAP+l0+tid]=pk_idx(p);
    }
  } // lc
  __syncthreads();
  for (int m=tid;m<MS;m+=256){
    unsigned long long p=rowpk[m];
    if (p) atomicMax(&g_rowpack[(size_t)bqn*MSP+m],p);
  }
}

// ---------------- K8: q_mask + masked-row compaction ------------------------
__global__ __launch_bounds__(256) void k_qmask(){
  int bq=blockIdx.x;
  int tid=threadIdx.x, lane=tid&63, w=tid>>6;
  __shared__ int wtot[4];
  int base=0;
  for (int m0=0;m0<MS;m0+=256){
    int m=m0+tid;
    bool qm=false;
    if (m<MS){
      unsigned bhv=0u; unsigned long long bp=0ull; int bn=0;
      #pragma unroll
      for (int n=0;n<NW;n++){
        unsigned long long pk=g_rowpack[(size_t)(bq*NW+n)*MSP+m];
        unsigned hv=(unsigned)(pk>>32);
        if (hv>bhv){bhv=hv;bp=pk;bn=n;}
      }
      int bl=pk_idx(bp);
      qm=(g_snear2[(size_t)(bq*NW+bn)*LTCAP+bl]==m);
    }
    unsigned long long bal=__ballot(qm);
    if (lane==0) wtot[w]=(int)__popcll(bal);
    __syncthreads();
    int wpre=0, tot=0;
    #pragma unroll
    for (int ww=0;ww<4;ww++){ if (ww<w) wpre+=wtot[ww]; tot+=wtot[ww]; }
    if (qm){
      int pre=(int)__popcll(bal&((1ull<<lane)-1ull));
      g_qmrows[bq*MSP+base+wpre+pre]=m;
    }
    base+=tot;
    __syncthreads();
  }
  if (tid==0) g_qmcount[bq]=base;
}

// ---------------- K9: pass B — masked rows only -----------------------------
__global__ __launch_bounds__(256) void k_passB(){
  int blk=blockIdx.x;
  int rt=blk%7; blk/=7;
  int n=blk%NW; blk/=NW;
  int bq=blk; int b=bq/Q;
  int nm=g_qmcount[bq];
  if (rt*64>=nm) return;
  int bqn=bq*NW+n;
  int Lt=MS+g_L[0];
  int nch=(Lt+63)>>6;
  int tid=threadIdx.x, tm=tid>>4, tl=tid&15;
  __shared__ __align__(16) float Qt[4096];
  __shared__ __align__(16) float KV[64*66];
  __shared__ __align__(16) float Pt[64*65];
  __shared__ int rows_s[64];
  if (tid<64){ int g=rt*64+tid; rows_s[tid]=(g<nm)?g_qmrows[bq*MSP+g]:0; }
  __syncthreads();
  const size_t qb=(size_t)bq*PD*MSP;
  const size_t kb=(size_t)(b*NW+n)*PD*LTCAP;
  for (int k=tid;k<4096;k+=256){
    int o=k>>6, rr=k&63;
    Qt[k]=(rt*64+rr<nm)?g_qproj[qb+(size_t)o*MSP+rows_s[rr]]:0.f;
  }
  float m_run[4], l_run[4], acc[4][4]={};
  #pragma unroll
  for (int i=0;i<4;i++){ m_run[i]=NEGF; l_run[i]=0.f; }
  for (int lc=0;lc<nch;lc++){
    int l0=lc<<6, lv=min(64,Lt-l0);
    __syncthreads();
    for (int k=tid;k<1024;k+=256){
      int o=k>>4, lq=k&15;
      *(float4*)&KV[o*64+lq*4]=*(const float4*)&g_ksup[kb+(size_t)o*LTCAP+l0+lq*4];
    }
    __syncthreads();
    float s[4][4]={};
    for (int c=0;c<64;c++){
      float a[4],bv[4];
      *(float4*)a =*(const float4*)&Qt[c*64+tm*4];
      *(float4*)bv=*(const float4*)&KV[c*64+tl*4];
      #pragma unroll
      for (int i=0;i<4;i++)
        #pragma unroll
        for (int j=0;j<4;j++) s[i][j]=fmaf(a[i],bv[j],s[i][j]);
    }
    #pragma unroll
    for (int i=0;i<4;i++)
      #pragma unroll
      for (int j=0;j<4;j++) s[i][j]=(tl*4+j<lv)?s[i][j]*0.125f:NEGF;
    #pragma unroll
    for (int i=0;i<4;i++){
      float mx=fmaxf(fmaxf(s[i][0],s[i][1]),fmaxf(s[i][2],s[i][3]));
      #pragma unroll
      for (int mk=1;mk<16;mk<<=1) mx=fmaxf(mx,__shfl_xor(mx,mk));
      float nm2=fmaxf(m_run[i],mx);
      float al=(m_run[i]<-1e37f)?0.f:__expf(m_run[i]-nm2);
      float ps=0.f;
      #pragma unroll
      for (int j=0;j<4;j++){
        float e=(s[i][j]<-1e37f)?0.f:__expf(s[i][j]-nm2);
        s[i][j]=e; ps+=e;
      }
      #pragma unroll
      for (int mk=1;mk<16;mk<<=1) ps+=__shfl_xor(ps,mk);
      l_run[i]=l_run[i]*al+ps; m_run[i]=nm2;
      #pragma unroll
      for (int j=0;j<4;j++) acc[i][j]*=al;
    }
    __syncthreads();
    #pragma unroll
    for (int i=0;i<4;i++)
      #pragma unroll
      for (int j=0;j<4;j++) Pt[(tm*4+i)*65+tl*4+j]=s[i][j];
    for (int k=tid;k<4096;k+=256){
      int o=k>>6, ll=k&63;
      KV[ll*66+o]=g_vsup[kb+(size_t)o*LTCAP+l0+ll];
    }
    __syncthreads();
    for (int l4=0;l4<64;l4+=4){
      float p[4][4];
      #pragma unroll
      for (int i=0;i<4;i++)
        #pragma unroll
        for (int u=0;u<4;u++) p[i][u]=Pt[(tm*4+i)*65+l4+u];
      #pragma unroll
      for (int u=0;u<4;u++){
        float2 v01=*(const float2*)&KV[(l4+u)*66+tl*4];
        float2 v23=*(const float2*)&KV[(l4+u)*66+tl*4+2];
        #pragma unroll
        for (int i=0;i<4;i++){
          acc[i][0]=fmaf(p[i][u],v01.x,acc[i][0]);
          acc[i][1]=fmaf(p[i][u],v01.y,acc[i][1]);
          acc[i][2]=fmaf(p[i][u],v23.x,acc[i][2]);
          acc[i][3]=fmaf(p[i][u],v23.y,acc[i][3]);
        }
      }
    }
  } // lc
  float rn[4];
  #pragma unroll
  for (int i=0;i<4;i++){
    float ss=0.f;
    #pragma unroll
    for (int j=0;j<4;j++){ acc[i][j]/=l_run[i]; ss=fmaf(acc[i][j],acc[i][j],ss); }
    #pragma unroll
    for (int mk=1;mk<16;mk<<=1) ss+=__shfl_xor(ss,mk);
    rn[i]=1.f/(sqrtf(ss)+1e-16f);
  }
  __syncthreads();
  #pragma unroll
  for (int i=0;i<4;i++)
    #pragma unroll
    for (int j=0;j<4;j++) Pt[(tm*4+i)*65+tl*4+j]=acc[i][j];
  int rowok[4];
  #pragma unroll
  for (int i=0;i<4;i++) rowok[i]=(rt*64+tm*4+i<nm);
  for (int kt=0;kt<7;kt++){
    __syncthreads();
    for (int k=tid;k<1024;k+=256){
      int o=k>>4, kq=k&15;
      *(float4*)&KV[o*64+kq*4]=*(const float4*)&g_vqn[qb+(size_t)o*MSP+kt*64+kq*4];
    }
    __syncthreads();
    float d[4][4]={};
    for (int o=0;o<64;o++){
      float a[4], bv4[4];
      #pragma unroll
      for (int i=0;i<4;i++) a[i]=Pt[(tm*4+i)*65+o];
      *(float4*)bv4=*(const float4*)&KV[o*64+tl*4];
      #pragma unroll
      for (int i=0;i<4;i++)
        #pragma unroll
        for (int j=0;j<4;j++) d[i][j]=fmaf(a[i],bv4[j],d[i][j]);
    }
    #pragma unroll
    for (int j=0;j<4;j++){
      int kg=kt*64+tl*4+j;
      float mv=NEGF;
      #pragma unroll
      for (int i=0;i<4;i++) if (rowok[i]) mv=fmaxf(mv,d[i][j]*rn[i]);
      mv=fmaxf(mv,__shfl_xor(mv,16));
      mv=fmaxf(mv,__shfl_xor(mv,32));
      if (((tid>>4)&3)==0 && kg<MS && mv>-1e37f)
        atomicMax(&g_cmax[(size_t)bqn*MSP+kg],enc_f(mv));
    }
  }
}

// ---------------- K10: logits (with fused vbar contribution) ----------------
__global__ __launch_bounds__(256) void k_logits(){
  int bqn=blockIdx.x;
  int n=bqn%NW, bq=bqn/NW, b=bq/Q;
  int tid=threadIdx.x;
  int nm=g_qmcount[bq];
  __shared__ float red[256];
  __shared__ float vb_s[64];
  if (tid<64) vb_s[tid]=g_vbarn[(b*NW+n)*PD+tid];
  __syncthreads();
  const float* vq=&g_vqn[(size_t)bq*PD*MSP];
  float p=0.f;
  for (int k=tid;k<MS;k+=256){
    float v=dec_f(g_cmax[(size_t)bqn*MSP+k]);
    if (nm<MS){
      float d=0.f;
      for (int o=0;o<PD;o++) d=fmaf(vb_s[o],vq[(size_t)o*MSP+k],d);
      v=fmaxf(v,d);
    }
    p+=(v+1.f)*0.5f;
  }
  red[tid]=p; __syncthreads();
  for (int s=128;s;s>>=1){ if (tid<s) red[tid]+=red[tid+s]; __syncthreads(); }
  if (tid==0) g_logits[bqn]=red[0];
}

// ---------------- K11: NLL loss ---------------------------------------------
__global__ void k_loss(const int* __restrict__ qy, float* __restrict__ out){
  int t=threadIdx.x;
  float lp=0.f;
  if (t<B*Q){
    int y=qy[t];
    float xv[NW]; float mxv=NEGF;
    #pragma unroll
    for (int n=0;n<NW;n++){ xv[n]=g_logits[t*NW+n]*5.f; mxv=fmaxf(mxv,xv[n]); }
    float s=0.f, xy=0.f;
    #pragma unroll
    for (int n=0;n<NW;n++){ s+=__expf(xv[n]-mxv); if (n==y) xy=xv[n]; }
    lp=xy-mxv-logf(s);
  }
  #pragma unroll
  for (int off=32;off;off>>=1) lp+=__shfl_down(lp,off);
  if (t==0) out[0]=-lp/(float)(B*Q);
}

extern "C" void kernel_launch(void* const* d_in, const int* in_sizes, int n_in,
                              void* d_out, int out_size, void* d_ws, size_t ws_size,
                              hipStream_t stream) {
  (void)in_sizes; (void)n_in; (void)out_size; (void)d_ws; (void)ws_size;
  const float* sup=(const float*)d_in[0];
  const float* qx =(const float*)d_in[2];
  const int*   qy =(const int*)d_in[3];
  const float* unl=(const float*)d_in[4];
  const float* kw =(const float*)d_in[5];
  const float* qw =(const float*)d_in[6];
  const float* vw =(const float*)d_in[7];
  float* out=(float*)d_out;

  k_init   <<<263,256,0,stream>>>();
  k_norms  <<<69,256,0,stream>>>(sup,unl);
  k_u2s    <<<B*138*6,256,0,stream>>>(sup,unl);
  k_compact<<<B*NW,256,0,stream>>>();
  k_kv     <<<B*NW*(LTCAP/64),256,0,stream>>>(sup,unl,kw,vw);
  k_vbar   <<<B*NW,256,0,stream>>>();
  k_qproj  <<<B*Q*7,256,0,stream>>>(qx,qw,vw);
  k_passA  <<<B*Q*NW*11,256,0,stream>>>();
  k_qmask  <<<B*Q,256,0,stream>>>();
  k_passB  <<<B*Q*NW*7,256,0,stream>>>();
  k_logits <<<B*Q*NW,256,0,stream>>>();
  k_loss   <<<1,64,0,stream>>>(qy,out);
}

// Round 4
// 829.677 us; speedup vs baseline: 2.3406x; 1.0528x over previous
//
#include <hip/hip_runtime.h>
#include <math.h>

#define B 2
#define Q 15
#define U 20
#define C 64
#define HW 441
#define NW 5
#define MU (U*HW)      // 8820
#define MS HW          // 441
#define NJ (NW*MS)     // 2205
#define PD 64
#define LCAP NJ
#define LTCAP 2688     // 42*64 >= 441+2205
#define MSP 448
#define NEGF (-3.402823466e38f)

// ---------------- device scratch (rewritten every call before any read) -----
__device__ float g_rnu[B*MU];
__device__ float g_rns[B*NJ];
__device__ unsigned long long g_snearpack[B*NJ];
__device__ unsigned long long g_unearpack[B*MU];
__device__ int   g_counts[B*NW];
__device__ int   g_L[1];
__device__ int   g_selidx[B*NW*LCAP];
__device__ float g_ksup[(size_t)B*NW*PD*LTCAP];
__device__ float g_vsup[(size_t)B*NW*PD*LTCAP];
__device__ float g_vbarn[B*NW*PD];
__device__ float g_qproj[(size_t)B*Q*PD*MSP];
__device__ float g_vqn[(size_t)B*Q*PD*MSP];
__device__ unsigned long long g_rowpack[(size_t)B*Q*NW*MSP];
__device__ unsigned long long g_snear2pack[(size_t)B*Q*NW*LTCAP];
__device__ int   g_qmrows[B*Q*MSP];
__device__ int   g_qmcount[B*Q];
__device__ unsigned g_cmax[(size_t)B*Q*NW*MSP];
__device__ float g_logits[B*Q*NW];

__device__ __forceinline__ unsigned enc_f(float f){
  unsigned b=__float_as_uint(f);
  return (b&0x80000000u)? ~b : (b|0x80000000u);
}
__device__ __forceinline__ float dec_f(unsigned k){
  unsigned b=(k&0x80000000u)?(k^0x80000000u):~k;
  return __uint_as_float(b);
}
__device__ __forceinline__ unsigned long long pk_make(float v,int idx){
  return ((unsigned long long)enc_f(v)<<32)|(unsigned)~(unsigned)idx;
}
__device__ __forceinline__ int pk_idx(unsigned long long p){
  return (int)~(unsigned)(p&0xFFFFFFFFull);
}

// ---------------- init ------------------------------------------------------
__global__ void k_init(){
  int i=blockIdx.x*256+threadIdx.x;
  if (i<B*NJ) g_snearpack[i]=0ull;
  if (i<B*MU) g_unearpack[i]=0ull;
  if (i<B*Q*NW*MSP){ g_rowpack[i]=0ull; g_cmax[i]=0u; }
  if (i<B*Q*NW*LTCAP) g_snear2pack[i]=0ull;
  if (i==0) g_L[0]=0;
}

// ---------------- K1: inverse column norms ---------------------------------
__global__ void k_norms(const float* __restrict__ sup, const float* __restrict__ unl){
  int i=blockIdx.x*256+threadIdx.x;
  if (i<B*MU){
    int b=i/MU, m=i%MU, ui=m/HW, p=m%HW;
    const float* base=unl+((size_t)(b*U+ui)*C)*HW+p;
    float ss=0.f;
    for (int c=0;c<C;c++){ float x=base[(size_t)c*HW]; ss+=x*x; }
    g_rnu[i]=1.f/fmaxf(sqrtf(ss),1e-12f);
  }
  if (i<B*NJ){
    int b=i/NJ, j=i%NJ, n=j/MS, s=j%MS;
    const float* base=sup+((size_t)(b*NW+n)*C)*HW+s;
    float ss=0.f;
    for (int c=0;c<C;c++){ float x=base[(size_t)c*HW]; ss+=x*x; }
    g_rns[i]=1.f/fmaxf(sqrtf(ss),1e-12f);
  }
}

// ---------------- K2: u2s — col-split 6x; 64x128 tiles; shuffle argmaxes ----
__global__ __launch_bounds__(256) void k_u2s(const float* __restrict__ sup, const float* __restrict__ unl){
  int blk=blockIdx.x;
  int grp=blk%6; blk/=6;
  int rb=blk%138; int b=blk/138;
  int mb=rb*64;
  int tid=threadIdx.x, tm=tid>>4, tl=tid&15;
  int lane=tid&63, w=tid>>6;
  __shared__ __align__(16) float Ut[4096];     // [c][m] 16KB
  __shared__ __align__(16) float Pt[8192];     // [c][j] 32KB
  __shared__ unsigned long long colred[512];   // [w][128] 4KB
  int mv=min(64,MU-mb);
  for (int k=tid;k<4096;k+=256){
    int c=k>>6, mm=k&63; float v=0.f;
    if (mm<mv){ int m=mb+mm, ui=m/HW, p=m%HW; v=unl[((size_t)(b*U+ui)*C+c)*HW+p]*g_rnu[b*MU+m]; }
    Ut[c*64+mm]=v;
  }
  unsigned long long rowpk[4]={0ull,0ull,0ull,0ull};
  for (int t=0;t<3;t++){
    int j0=(grp*3+t)*128;
    int jv=min(128,NJ-j0);
    __syncthreads();
    for (int k=tid;k<8192;k+=256){
      int c=k>>7, jj=k&127; float v=0.f;
      if (jj<jv){ int j=j0+jj, n=j/MS, s=j%MS; v=sup[((size_t)(b*NW+n)*C+c)*HW+s]*g_rns[b*NJ+j]; }
      Pt[c*128+jj]=v;
    }
    __syncthreads();
    float s[4][8]={};
    for (int c=0;c<64;c++){
      float a[4],b0[4],b1[4];
      *(float4*)a =*(const float4*)&Ut[c*64+tm*4];
      *(float4*)b0=*(const float4*)&Pt[c*128+tl*4];
      *(float4*)b1=*(const float4*)&Pt[c*128+64+tl*4];
      #pragma unroll
      for (int i=0;i<4;i++)
        #pragma unroll
        for (int j=0;j<4;j++){ s[i][j]=fmaf(a[i],b0[j],s[i][j]); s[i][j+4]=fmaf(a[i],b1[j],s[i][j+4]); }
    }
    #pragma unroll
    for (int i=0;i<4;i++){
      if (tm*4+i<mv){
        unsigned long long p=rowpk[i];
        #pragma unroll
        for (int j=0;j<8;j++){
          int jj=(j<4)?(tl*4+j):(64+tl*4+(j-4));
          if (jj<jv){
            unsigned long long c2=pk_make(s[i][j],j0+jj);
            if (c2>p) p=c2;
          }
        }
        rowpk[i]=p;
      }
    }
    unsigned long long cpk[8];
    #pragma unroll
    for (int j=0;j<8;j++){
      unsigned long long p=0ull;
      #pragma unroll
      for (int i=0;i<4;i++){
        if (tm*4+i<mv){
          unsigned long long c2=pk_make(s[i][j],mb+tm*4+i);
          if (c2>p) p=c2;
        }
      }
      cpk[j]=p;
    }
    #pragma unroll
    for (int j=0;j<8;j++){
      unsigned long long o;
      o=__shfl_xor(cpk[j],16); if (o>cpk[j]) cpk[j]=o;
      o=__shfl_xor(cpk[j],32); if (o>cpk[j]) cpk[j]=o;
    }
    if ((lane>>4)==0){
      #pragma unroll
      for (int j=0;j<8;j++){
        int jj=(j<4)?(tl*4+j):(64+tl*4+(j-4));
        colred[w*128+jj]=cpk[j];
      }
    }
    __syncthreads();
    if (tid<128 && tid<jv){
      unsigned long long p=colred[tid];
      if (colred[128+tid]>p) p=colred[128+tid];
      if (colred[256+tid]>p) p=colred[256+tid];
      if (colred[384+tid]>p) p=colred[384+tid];
      if (p) atomicMax(&g_snearpack[b*NJ+j0+tid],p);
    }
  }
  #pragma unroll
  for (int i=0;i<4;i++){
    unsigned long long p=rowpk[i];
    #pragma unroll
    for (int mk=1;mk<16;mk<<=1){ unsigned long long o=__shfl_xor(p,mk); if (o>p) p=o; }
    if (tl==0 && tm*4+i<mv && p) atomicMax(&g_unearpack[b*MU+mb+tm*4+i],p);
  }
}

// ---------------- K4: mutual check + stable compaction; counts; L ----------
__global__ __launch_bounds__(256) void k_compact(){
  int b=blockIdx.x/NW, n=blockIdx.x%NW;
  int tid=threadIdx.x, lane=tid&63, w=tid>>6;
  __shared__ int wtot[4];
  int base=0;
  for (int m0=0;m0<MU;m0+=256){
    int m=m0+tid;
    bool flag=false;
    if (m<MU){
      int j=pk_idx(g_unearpack[b*MU+m]);
      flag=(j/MS==n) && (pk_idx(g_snearpack[b*NJ+j])==m);
    }
    unsigned long long bal=__ballot(flag);
    if (lane==0) wtot[w]=(int)__popcll(bal);
    __syncthreads();
    int wpre=0, tot=0;
    #pragma unroll
    for (int ww=0;ww<4;ww++){ if (ww<w) wpre+=wtot[ww]; tot+=wtot[ww]; }
    if (flag){
      int pre=(int)__popcll(bal&((1ull<<lane)-1ull));
      g_selidx[(b*NW+n)*LCAP+base+wpre+pre]=m;
    }
    base+=tot;
    __syncthreads();
  }
  if (tid==0){ g_counts[b*NW+n]=base; atomicMax(&g_L[0],base); }
}

// ---------------- K5: k_sup / v_sup (zero-filled to Lt; 256 thr, o-split) ---
__global__ __launch_bounds__(256) void k_kv(const float* __restrict__ sup, const float* __restrict__ unl,
                                            const float* __restrict__ kw, const float* __restrict__ vw){
  int blk=blockIdx.x;
  int lb=blk%(LTCAP/64); blk/=(LTCAP/64);
  int n=blk%NW, b=blk/NW;
  int Lt=MS+g_L[0];
  if (lb*64>=Lt) return;
  int cnt=g_counts[b*NW+n];
  int tid=threadIdx.x, lane=tid&63, w=tid>>6;
  __shared__ float F[4096];
  __shared__ const float* ptr_s[64];
  if (tid<64){
    int l=lb*64+tid;
    const float* p=nullptr;
    if (l<MS) p=&sup[((size_t)(b*NW+n)*C)*HW+l];
    else if (l<MS+cnt){
      int mg=g_selidx[(b*NW+n)*LCAP+(l-MS)];
      int ui=mg/HW, pp=mg%HW;
      p=&unl[((size_t)(b*U+ui)*C)*HW+pp];
    }
    ptr_s[tid]=p;
  }
  __syncthreads();
  for (int k=tid;k<4096;k+=256){
    int c=k>>6, ll=k&63;
    const float* p=ptr_s[ll];
    F[c*64+ll]=p?p[(size_t)c*HW]:0.f;
  }
  __syncthreads();
  int l=lb*64+lane;
  size_t ob=((size_t)(b*NW+n)*PD)*LTCAP+l;
  for (int oo=0;oo<16;oo++){
    int o=w*16+oo;
    float ka=0.f, va=0.f;
    for (int c=0;c<C;c++){ float f=F[c*64+lane]; ka=fmaf(kw[o*C+c],f,ka); va=fmaf(vw[o*C+c],f,va); }
    g_ksup[ob+(size_t)o*LTCAP]=ka;
    g_vsup[ob+(size_t)o*LTCAP]=va;
  }
}

// ---------------- K5b: normalized vbar = mean_l v_sup, L2-normalized --------
__global__ __launch_bounds__(256) void k_vbar(){
  int bn=blockIdx.x;
  int tid=threadIdx.x, lane=tid&63, w=tid>>6;
  int cnt=g_counts[bn];
  int Lt=MS+g_L[0];
  __shared__ float vb_s[64];
  for (int oo=0;oo<16;oo++){
    int o=w*16+oo;
    const float* row=&g_vsup[((size_t)bn*PD+o)*LTCAP];
    float s=0.f;
    for (int l=lane;l<MS+cnt;l+=64) s+=row[l];
    #pragma unroll
    for (int mk=1;mk<64;mk<<=1) s+=__shfl_xor(s,mk);
    if (lane==0) vb_s[o]=s/(float)Lt;
  }
  __syncthreads();
  if (tid<64){
    float v=vb_s[tid];
    float ss=v*v;
    #pragma unroll
    for (int mk=1;mk<64;mk<<=1) ss+=__shfl_xor(ss,mk);
    g_vbarn[bn*PD+tid]=v/(sqrtf(ss)+1e-16f);
  }
}

// ---------------- K6: q_proj / normalized v_query (256 thr, o-split) --------
__global__ __launch_bounds__(256) void k_qproj(const float* __restrict__ qx, const float* __restrict__ qw,
                                               const float* __restrict__ vw){
  int blk=blockIdx.x;
  int mt=blk%7; blk/=7;
  int bq=blk;
  int tid=threadIdx.x, lane=tid&63, w=tid>>6;
  __shared__ float F[4096];
  __shared__ float ssp[256];
  for (int k=tid;k<4096;k+=256){
    int c=k>>6, mm=k&63, m=mt*64+mm;
    F[c*64+mm]=(m<MS)?qx[((size_t)bq*C+c)*HW+m]:0.f;
  }
  __syncthreads();
  int m=mt*64+lane;
  size_t ob=(size_t)bq*PD*MSP+m;
  float va[16]; float ssl=0.f;
  for (int oo=0;oo<16;oo++){
    int o=w*16+oo;
    float qa=0.f, v=0.f;
    for (int c=0;c<C;c++){ float f=F[c*64+lane]; qa=fmaf(qw[o*C+c],f,qa); v=fmaf(vw[o*C+c],f,v); }
    g_qproj[ob+(size_t)o*MSP]=qa;
    va[oo]=v; ssl=fmaf(v,v,ssl);
  }
  ssp[tid]=ssl;
  __syncthreads();
  float ss=ssp[lane]+ssp[64+lane]+ssp[128+lane]+ssp[192+lane];
  float rn=1.f/(sqrtf(ss)+1e-16f);
  for (int oo=0;oo<16;oo++) g_vqn[ob+(size_t)(w*16+oo)*MSP]=va[oo]*rn;
}

// ---------------- K7: pass A — inverted: block=(bqn, m-block-128); 8x4 micro
__global__ __launch_bounds__(256) void k_passA(){
  int blk=blockIdx.x;
  int mh=blk%4; blk/=4;
  int n=blk%NW; blk/=NW;
  int bq=blk; int b=bq/Q;
  int Lt=MS+g_L[0];
  int nch=(Lt+63)>>6;
  int tid=threadIdx.x, tm=tid>>4, tl=tid&15;
  int lane=tid&63, w=tid>>6;
  int bqn=bq*NW+n;
  int m0=mh*128;
  __shared__ __align__(16) float Qt[8192];     // [o][mm], mm in 0..127 (32KB)
  __shared__ __align__(16) float Kt[4096];     // [o][l]  (16KB)
  __shared__ unsigned long long colred[256];   // [w][64] (2KB)
  const size_t qb=(size_t)bq*PD*MSP;
  const size_t kb=(size_t)(b*NW+n)*PD*LTCAP;
  // stage Q tile once (zeros beyond MSP)
  for (int k=tid;k<2048;k+=256){
    int o=k>>5, mq=k&31;
    int m=m0+mq*4;
    float4 v=make_float4(0.f,0.f,0.f,0.f);
    if (m<MSP) v=*(const float4*)&g_qproj[qb+(size_t)o*MSP+m];
    *(float4*)&Qt[o*128+mq*4]=v;
  }
  unsigned long long rowpk[8]={0ull,0ull,0ull,0ull,0ull,0ull,0ull,0ull};
  for (int lc=0;lc<nch;lc++){
    int l0=lc<<6, lv=min(64,Lt-l0);
    __syncthreads();               // Qt ready / prev GEMM reads of Kt done
    for (int k=tid;k<1024;k+=256){
      int o=k>>4, lq=k&15;
      *(float4*)&Kt[o*64+lq*4]=*(const float4*)&g_ksup[kb+(size_t)o*LTCAP+l0+lq*4];
    }
    __syncthreads();
    float s[8][4]={};
    for (int c=0;c<64;c++){
      float a[8],bv[4];
      *(float4*)&a[0]=*(const float4*)&Qt[c*128+tm*8];
      *(float4*)&a[4]=*(const float4*)&Qt[c*128+tm*8+4];
      *(float4*)bv=*(const float4*)&Kt[c*64+tl*4];
      #pragma unroll
      for (int i=0;i<8;i++)
        #pragma unroll
        for (int j=0;j<4;j++) s[i][j]=fmaf(a[i],bv[j],s[i][j]);
    }
    #pragma unroll
    for (int i=0;i<8;i++)
      #pragma unroll
      for (int j=0;j<4;j++) s[i][j]*=0.125f;
    // row-best over l (accumulate in regs across chunks)
    #pragma unroll
    for (int i=0;i<8;i++){
      int m=m0+tm*8+i;
      if (m<MS){
        unsigned long long p=rowpk[i];
        #pragma unroll
        for (int j=0;j<4;j++){
          if (tl*4+j<lv){
            unsigned long long c2=pk_make(s[i][j],l0+tl*4+j);
            if (c2>p) p=c2;
          }
        }
        rowpk[i]=p;
      }
    }
    // col-best over this block's 128 rows -> cross-block atomic merge
    unsigned long long cpk[4];
    #pragma unroll
    for (int j=0;j<4;j++){
      unsigned long long p=0ull;
      #pragma unroll
      for (int i=0;i<8;i++){
        int m=m0+tm*8+i;
        if (m<MS){
          unsigned long long c2=pk_make(s[i][j],m);
          if (c2>p) p=c2;
        }
      }
      cpk[j]=p;
    }
    #pragma unroll
    for (int j=0;j<4;j++){
      unsigned long long o;
      o=__shfl_xor(cpk[j],16); if (o>cpk[j]) cpk[j]=o;
      o=__shfl_xor(cpk[j],32); if (o>cpk[j]) cpk[j]=o;
    }
    if ((lane>>4)==0){
      #pragma unroll
      for (int j=0;j<4;j++) colred[w*64+tl*4+j]=cpk[j];
    }
    __syncthreads();
    if (tid<64 && tid<lv){
      unsigned long long p=colred[tid];
      if (colred[64+tid]>p) p=colred[64+tid];
      if (colred[128+tid]>p) p=colred[128+tid];
      if (colred[192+tid]>p) p=colred[192+tid];
      if (p) atomicMax(&g_snear2pack[(size_t)bqn*LTCAP+l0+tid],p);
    }
  } // lc
  // finalize row-best (reduce over tl group, atomic across m-blocks)
  #pragma unroll
  for (int i=0;i<8;i++){
    int m=m0+tm*8+i;
    unsigned long long p=rowpk[i];
    #pragma unroll
    for (int mk=1;mk<16;mk<<=1){ unsigned long long o=__shfl_xor(p,mk); if (o>p) p=o; }
    if (tl==0 && m<MS && p) atomicMax(&g_rowpack[(size_t)bqn*MSP+m],p);
  }
}

// ---------------- K8: q_mask + masked-row compaction ------------------------
__global__ __launch_bounds__(256) void k_qmask(){
  int bq=blockIdx.x;
  int tid=threadIdx.x, lane=tid&63, w=tid>>6;
  __shared__ int wtot[4];
  int base=0;
  for (int m0=0;m0<MS;m0+=256){
    int m=m0+tid;
    bool qm=false;
    if (m<MS){
      unsigned bhv=0u; unsigned long long bp=0ull; int bn=0;
      #pragma unroll
      for (int n=0;n<NW;n++){
        unsigned long long pk=g_rowpack[(size_t)(bq*NW+n)*MSP+m];
        unsigned hv=(unsigned)(pk>>32);
        if (hv>bhv){bhv=hv;bp=pk;bn=n;}
      }
      int bl=pk_idx(bp);
      qm=(pk_idx(g_snear2pack[(size_t)(bq*NW+bn)*LTCAP+bl])==m);
    }
    unsigned long long bal=__ballot(qm);
    if (lane==0) wtot[w]=(int)__popcll(bal);
    __syncthreads();
    int wpre=0, tot=0;
    #pragma unroll
    for (int ww=0;ww<4;ww++){ if (ww<w) wpre+=wtot[ww]; tot+=wtot[ww]; }
    if (qm){
      int pre=(int)__popcll(bal&((1ull<<lane)-1ull));
      g_qmrows[bq*MSP+base+wpre+pre]=m;
    }
    base+=tot;
    __syncthreads();
  }
  if (tid==0) g_qmcount[bq]=base;
}

// ---------------- K9: pass B — masked rows only -----------------------------
__global__ __launch_bounds__(256) void k_passB(){
  int blk=blockIdx.x;
  int rt=blk%7; blk/=7;
  int n=blk%NW; blk/=NW;
  int bq=blk; int b=bq/Q;
  int nm=g_qmcount[bq];
  if (rt*64>=nm) return;
  int bqn=bq*NW+n;
  int Lt=MS+g_L[0];
  int nch=(Lt+63)>>6;
  int tid=threadIdx.x, tm=tid>>4, tl=tid&15;
  __shared__ __align__(16) float Qt[4096];
  __shared__ __align__(16) float KV[64*66];
  __shared__ __align__(16) float Pt[64*65];
  __shared__ int rows_s[64];
  if (tid<64){ int g=rt*64+tid; rows_s[tid]=(g<nm)?g_qmrows[bq*MSP+g]:0; }
  __syncthreads();
  const size_t qb=(size_t)bq*PD*MSP;
  const size_t kb=(size_t)(b*NW+n)*PD*LTCAP;
  for (int k=tid;k<4096;k+=256){
    int o=k>>6, rr=k&63;
    Qt[k]=(rt*64+rr<nm)?g_qproj[qb+(size_t)o*MSP+rows_s[rr]]:0.f;
  }
  float m_run[4], l_run[4], acc[4][4]={};
  #pragma unroll
  for (int i=0;i<4;i++){ m_run[i]=NEGF; l_run[i]=0.f; }
  for (int lc=0;lc<nch;lc++){
    int l0=lc<<6, lv=min(64,Lt-l0);
    __syncthreads();
    for (int k=tid;k<1024;k+=256){
      int o=k>>4, lq=k&15;
      *(float4*)&KV[o*64+lq*4]=*(const float4*)&g_ksup[kb+(size_t)o*LTCAP+l0+lq*4];
    }
    __syncthreads();
    float s[4][4]={};
    for (int c=0;c<64;c++){
      float a[4],bv[4];
      *(float4*)a =*(const float4*)&Qt[c*64+tm*4];
      *(float4*)bv=*(const float4*)&KV[c*64+tl*4];
      #pragma unroll
      for (int i=0;i<4;i++)
        #pragma unroll
        for (int j=0;j<4;j++) s[i][j]=fmaf(a[i],bv[j],s[i][j]);
    }
    #pragma unroll
    for (int i=0;i<4;i++)
      #pragma unroll
      for (int j=0;j<4;j++) s[i][j]=(tl*4+j<lv)?s[i][j]*0.125f:NEGF;
    #pragma unroll
    for (int i=0;i<4;i++){
      float mx=fmaxf(fmaxf(s[i][0],s[i][1]),fmaxf(s[i][2],s[i][3]));
      #pragma unroll
      for (int mk=1;mk<16;mk<<=1) mx=fmaxf(mx,__shfl_xor(mx,mk));
      float nm2=fmaxf(m_run[i],mx);
      float al=(m_run[i]<-1e37f)?0.f:__expf(m_run[i]-nm2);
      float ps=0.f;
      #pragma unroll
      for (int j=0;j<4;j++){
        float e=(s[i][j]<-1e37f)?0.f:__expf(s[i][j]-nm2);
        s[i][j]=e; ps+=e;
      }
      #pragma unroll
      for (int mk=1;mk<16;mk<<=1) ps+=__shfl_xor(ps,mk);
      l_run[i]=l_run[i]*al+ps; m_run[i]=nm2;
      #pragma unroll
      for (int j=0;j<4;j++) acc[i][j]*=al;
    }
    __syncthreads();
    #pragma unroll
    for (int i=0;i<4;i++)
      #pragma unroll
      for (int j=0;j<4;j++) Pt[(tm*4+i)*65+tl*4+j]=s[i][j];
    for (int k=tid;k<4096;k+=256){
      int o=k>>6, ll=k&63;
      KV[ll*66+o]=g_vsup[kb+(size_t)o*LTCAP+l0+ll];
    }
    __syncthreads();
    for (int l4=0;l4<64;l4+=4){
      float p[4][4];
      #pragma unroll
      for (int i=0;i<4;i++)
        #pragma unroll
        for (int u=0;u<4;u++) p[i][u]=Pt[(tm*4+i)*65+l4+u];
      #pragma unroll
      for (int u=0;u<4;u++){
        float2 v01=*(const float2*)&KV[(l4+u)*66+tl*4];
        float2 v23=*(const float2*)&KV[(l4+u)*66+tl*4+2];
        #pragma unroll
        for (int i=0;i<4;i++){
          acc[i][0]=fmaf(p[i][u],v01.x,acc[i][0]);
          acc[i][1]=fmaf(p[i][u],v01.y,acc[i][1]);
          acc[i][2]=fmaf(p[i][u],v23.x,acc[i][2]);
          acc[i][3]=fmaf(p[i][u],v23.y,acc[i][3]);
        }
      }
    }
  } // lc
  float rn[4];
  #pragma unroll
  for (int i=0;i<4;i++){
    float ss=0.f;
    #pragma unroll
    for (int j=0;j<4;j++){ acc[i][j]/=l_run[i]; ss=fmaf(acc[i][j],acc[i][j],ss); }
    #pragma unroll
    for (int mk=1;mk<16;mk<<=1) ss+=__shfl_xor(ss,mk);
    rn[i]=1.f/(sqrtf(ss)+1e-16f);
  }
  __syncthreads();
  #pragma unroll
  for (int i=0;i<4;i++)
    #pragma unroll
    for (int j=0;j<4;j++) Pt[(tm*4+i)*65+tl*4+j]=acc[i][j];
  int rowok[4];
  #pragma unroll
  for (int i=0;i<4;i++) rowok[i]=(rt*64+tm*4+i<nm);
  for (int kt=0;kt<7;kt++){
    __syncthreads();
    for (int k=tid;k<1024;k+=256){
      int o=k>>4, kq=k&15;
      *(float4*)&KV[o*64+kq*4]=*(const float4*)&g_vqn[qb+(size_t)o*MSP+kt*64+kq*4];
    }
    __syncthreads();
    float d[4][4]={};
    for (int o=0;o<64;o++){
      float a[4], bv4[4];
      #pragma unroll
      for (int i=0;i<4;i++) a[i]=Pt[(tm*4+i)*65+o];
      *(float4*)bv4=*(const float4*)&KV[o*64+tl*4];
      #pragma unroll
      for (int i=0;i<4;i++)
        #pragma unroll
        for (int j=0;j<4;j++) d[i][j]=fmaf(a[i],bv4[j],d[i][j]);
    }
    #pragma unroll
    for (int j=0;j<4;j++){
      int kg=kt*64+tl*4+j;
      float mv=NEGF;
      #pragma unroll
      for (int i=0;i<4;i++) if (rowok[i]) mv=fmaxf(mv,d[i][j]*rn[i]);
      mv=fmaxf(mv,__shfl_xor(mv,16));
      mv=fmaxf(mv,__shfl_xor(mv,32));
      if (((tid>>4)&3)==0 && kg<MS && mv>-1e37f)
        atomicMax(&g_cmax[(size_t)bqn*MSP+kg],enc_f(mv));
    }
  }
}

// ---------------- K10: logits (with fused vbar contribution) ----------------
__global__ __launch_bounds__(256) void k_logits(){
  int bqn=blockIdx.x;
  int n=bqn%NW, bq=bqn/NW, b=bq/Q;
  int tid=threadIdx.x;
  int nm=g_qmcount[bq];
  __shared__ float red[256];
  __shared__ float vb_s[64];
  if (tid<64) vb_s[tid]=g_vbarn[(b*NW+n)*PD+tid];
  __syncthreads();
  const float* vq=&g_vqn[(size_t)bq*PD*MSP];
  float p=0.f;
  for (int k=tid;k<MS;k+=256){
    float v=dec_f(g_cmax[(size_t)bqn*MSP+k]);
    if (nm<MS){
      float d=0.f;
      for (int o=0;o<PD;o++) d=fmaf(vb_s[o],vq[(size_t)o*MSP+k],d);
      v=fmaxf(v,d);
    }
    p+=(v+1.f)*0.5f;
  }
  red[tid]=p; __syncthreads();
  for (int s=128;s;s>>=1){ if (tid<s) red[tid]+=red[tid+s]; __syncthreads(); }
  if (tid==0) g_logits[bqn]=red[0];
}

// ---------------- K11: NLL loss ---------------------------------------------
__global__ void k_loss(const int* __restrict__ qy, float* __restrict__ out){
  int t=threadIdx.x;
  float lp=0.f;
  if (t<B*Q){
    int y=qy[t];
    float xv[NW]; float mxv=NEGF;
    #pragma unroll
    for (int n=0;n<NW;n++){ xv[n]=g_logits[t*NW+n]*5.f; mxv=fmaxf(mxv,xv[n]); }
    float s=0.f, xy=0.f;
    #pragma unroll
    for (int n=0;n<NW;n++){ s+=__expf(xv[n]-mxv); if (n==y) xy=xv[n]; }
    lp=xy-mxv-logf(s);
  }
  #pragma unroll
  for (int off=32;off;off>>=1) lp+=__shfl_down(lp,off);
  if (t==0) out[0]=-lp/(float)(B*Q);
}

extern "C" void kernel_launch(void* const* d_in, const int* in_sizes, int n_in,
                              void* d_out, int out_size, void* d_ws, size_t ws_size,
                              hipStream_t stream) {
  (void)in_sizes; (void)n_in; (void)out_size; (void)d_ws; (void)ws_size;
  const float* sup=(const float*)d_in[0];
  const float* qx =(const float*)d_in[2];
  const int*   qy =(const int*)d_in[3];
  const float* unl=(const float*)d_in[4];
  const float* kw =(const float*)d_in[5];
  const float* qw =(const float*)d_in[6];
  const float* vw =(const float*)d_in[7];
  float* out=(float*)d_out;

  k_init   <<<1575,256,0,stream>>>();
  k_norms  <<<69,256,0,stream>>>(sup,unl);
  k_u2s    <<<B*138*6,256,0,stream>>>(sup,unl);
  k_compact<<<B*NW,256,0,stream>>>();
  k_kv     <<<B*NW*(LTCAP/64),256,0,stream>>>(sup,unl,kw,vw);
  k_vbar   <<<B*NW,256,0,stream>>>();
  k_qproj  <<<B*Q*7,256,0,stream>>>(qx,qw,vw);
  k_passA  <<<B*Q*NW*4,256,0,stream>>>();
  k_qmask  <<<B*Q,256,0,stream>>>();
  k_passB  <<<B*Q*NW*7,256,0,stream>>>();
  k_logits <<<B*Q*NW,256,0,stream>>>();
  k_loss   <<<1,64,0,stream>>>(qy,out);
}